// Round 5
// baseline (1167.698 us; speedup 1.0000x reference)
//
#include <hip/hip_runtime.h>
#include <cstddef>
#include <cstdint>

typedef unsigned short ushort_t;
typedef __attribute__((ext_vector_type(8))) short bf16x8;
typedef __attribute__((ext_vector_type(4))) float f32x4;

#define Bb 256
#define Hh 1024
#define Ff 512
#define Tt 128

// ---------- helpers ----------
__device__ __forceinline__ ushort_t f2bf(float f) {
    unsigned int u = __float_as_uint(f);
    unsigned int r = (u + 0x7FFFu + ((u >> 16) & 1u)) >> 16;
    return (ushort_t)r;
}
__device__ __forceinline__ float sigf(float x)  { return 1.0f / (1.0f + __expf(-x)); }
__device__ __forceinline__ float tanhf_(float x){ return 2.0f / (1.0f + __expf(-2.0f * x)) - 1.0f; }

// ---------- weight swizzle: row-major fp32 [K][N] -> bf16 B-fragment blocks ----------
// 1KB blocks [ntile][kstep]; within: lane=(koff/8)*16+(n%16), j=koff%8.
// modes 0/1: gate-interleaved ntile = ugroup*4 + gate. mode 2 (Wd): plain.
__global__ void swz(const float* __restrict__ s0, const float* __restrict__ s1,
                    ushort_t* __restrict__ dst, int K, int N, int mode, int total)
{
    int KB = K >> 5;
    for (int idx = blockIdx.x * blockDim.x + threadIdx.x; idx < total;
         idx += gridDim.x * blockDim.x) {
        int blk   = idx >> 9;
        int lane  = (idx >> 3) & 63;
        int j     = idx & 7;
        int ntile = blk / KB;
        int kstep = blk - ntile * KB;
        int k = (kstep << 5) + ((lane >> 4) << 3) + j;
        int n;
        if (mode == 2) n = (ntile << 4) + (lane & 15);
        else           n = ((ntile & 3) << 10) + ((ntile >> 2) << 4) + (lane & 15);
        float v;
        if (mode == 0)      v = s0[(size_t)k * N + n] + s1[(size_t)k * N + n];
        else if (mode == 1) v = (k < 1024) ? s0[(size_t)k * N + n]
                                           : s1[(size_t)(k - 1024) * N + n];
        else                v = s0[(size_t)k * N + n];
        dst[idx] = f2bf(v);
    }
}

// ---------- A0 = [x0 | h0] as bf16, row-major [256][2048] ----------
__global__ void mk_a0(const float* __restrict__ x0, const float* __restrict__ h0,
                      ushort_t* __restrict__ a0)
{
    int idx = blockIdx.x * blockDim.x + threadIdx.x;
    if (idx >= Bb * 2048) return;
    int r = idx >> 11, k = idx & 2047;
    float v = (k < 1024) ? x0[r * 1024 + k] : h0[r * 1024 + k - 1024];
    a0[idx] = f2bf(v);
}

__global__ void zero_bar(int* bar) {
    int i = blockIdx.x * blockDim.x + threadIdx.x;
    if (i < 1024) bar[i] = 0;
}

// bar layout (ints, 128B-spaced lines):
//   bar[g*32] : arrival counter for logical group g = blockIdx&7 (32 blocks).
//   All ops agent-scope RMW -> execute at the coherent point (LLC): converges
//   for ANY block->XCD placement (proven r4).

// ---------- step 0 (K=2048, Mcat streamed): round-2 kernel, proven ----------
__global__ __launch_bounds__(256) void lstm_step(
    const ushort_t* __restrict__ Ap, int K,
    const ushort_t* __restrict__ Bw,
    const float* cin, float* cout,
    ushort_t* __restrict__ seqt,
    const float* __restrict__ bias)
{
    __shared__ __align__(16) ushort_t lA[32 * 512];
    __shared__ __align__(16) ushort_t lB[32 * 512];

    const int tid = threadIdx.x, w = tid >> 6, lane = tid & 63;
    const int id = blockIdx.x;
    const int ntg = ((id & 7) << 3) | (id >> 5);
    const int bt  = (id >> 3) & 3;
    const int r0 = bt << 6, hb = ntg << 4;
    const int wr = w >> 1, wc = w & 1;
    const int KB = K >> 5;

    f32x4 acc[2][2];
    #pragma unroll
    for (int m = 0; m < 2; ++m)
        #pragma unroll
        for (int n = 0; n < 2; ++n) acc[m][n] = (f32x4){0.f, 0.f, 0.f, 0.f};

    const int kp = tid & 31;
    const int q_a = kp & 3, kk_a = kp >> 2;

    for (int kc = 0; kc < K; kc += 256) {
        bf16x8 va[8];
        #pragma unroll
        for (int i = 0; i < 8; ++i) {
            int row = (i << 3) + (tid >> 5);
            va[i] = *(const bf16x8*)(Ap + (size_t)(r0 + row) * K + kc + (kp << 3));
        }
        bf16x8 vb[8];
        #pragma unroll
        for (int i = 0; i < 8; ++i)
            vb[i] = *(const bf16x8*)(Bw +
                ((((size_t)((ntg << 2) + w)) * KB + (kc >> 5) + i) << 9) + (lane << 3));
        #pragma unroll
        for (int i = 0; i < 8; ++i) {
            int row = (i << 3) + (tid >> 5);
            int msub = row >> 4, mm = row & 15;
            int pos = (q_a << 4) | (mm ^ (((kk_a << 2) + q_a) & 15));
            *(bf16x8*)&lA[((((kk_a << 2) + msub) << 6) + pos) << 3] = va[i];
        }
        #pragma unroll
        for (int i = 0; i < 8; ++i)
            *(bf16x8*)&lB[(((i << 2) + w) << 9) + (lane << 3)] = vb[i];
        __syncthreads();

        #pragma unroll
        for (int kk = 0; kk < 8; ++kk) {
            const int qq = lane >> 4, mm = lane & 15;
            const int pos = (qq << 4) | (mm ^ (((kk << 2) + qq) & 15));
            bf16x8 af[2], bfr[2];
            #pragma unroll
            for (int m = 0; m < 2; ++m)
                af[m] = *(const bf16x8*)&lA[((((kk << 2) + (wr << 1) + m) << 6) + pos) << 3];
            #pragma unroll
            for (int n = 0; n < 2; ++n)
                bfr[n] = *(const bf16x8*)&lB[((((kk << 2) + (wc << 1) + n) << 6) + lane) << 3];
            #pragma unroll
            for (int m = 0; m < 2; ++m)
                #pragma unroll
                for (int n = 0; n < 2; ++n)
                    acc[m][n] = __builtin_amdgcn_mfma_f32_16x16x32_bf16(
                        af[m], bfr[n], acc[m][n], 0, 0, 0);
        }
        __syncthreads();
    }

    float* lZ = (float*)lA;
    {
        int q = lane >> 4, nl = lane & 15;
        #pragma unroll
        for (int m = 0; m < 2; ++m)
            #pragma unroll
            for (int n = 0; n < 2; ++n)
                #pragma unroll
                for (int r = 0; r < 4; ++r)
                    lZ[((wr << 5) + (m << 4) + (q << 2) + r) * 68 +
                       (wc << 5) + (n << 4) + nl] = acc[m][n][r];
    }
    __syncthreads();

    #pragma unroll
    for (int i = 0; i < 4; ++i) {
        int idx = (i << 8) + tid;
        int row = idx >> 4, u = idx & 15;
        float zi = lZ[row * 68 +      u] + bias[       hb + u];
        float zf = lZ[row * 68 + 16 + u] + bias[1024 + hb + u];
        float zg = lZ[row * 68 + 32 + u] + bias[2048 + hb + u];
        float zo = lZ[row * 68 + 48 + u] + bias[3072 + hb + u];
        size_t cidx = (size_t)(r0 + row) * Hh + hb + u;
        float cp = cin[cidx];
        float cn = sigf(zf) * cp + sigf(zi) * tanhf_(zg);
        cout[cidx] = cn;
        seqt[cidx] = f2bf(sigf(zo) * tanhf_(cn));
    }
}

// ---------- persistent scan, steps 1..127 — K-split waves, 2-partial reduce ----------
// Group g = id&7 owns rows [32g,32g+32); block s = id>>3 owns h-cols [32s,32s+32)
// (Z tile 32x128). Wave (kw,nw)=(w>>1,w&1): kw = K-span [512kw,512kw+512);
// computes the FULL 32x128 Z partial for its K-span (af reads 32/wave vs r4's
// 64 — kills the 4x redundant A reads); nw = staging row-half + ntile ul role.
// Per step: ONE staging sync (wave-pair fills its region), MFMA (no barriers),
// Zp write, sync, 2-partial reduce + gates. B-frags Brg[4][16] (compiler may
// rematerialize from cache — r4 evidence, fine). Publish/barrier = proven r4
// primitives (agent-scope exchange + RMW arrival/poll), poll s_sleep(1).
__global__ __launch_bounds__(256, 1) void lstm_scan(
    ushort_t* __restrict__ seq,
    const ushort_t* __restrict__ Msum,
    const float* __restrict__ bias,
    const float* __restrict__ cin,
    int* __restrict__ bar)
{
    __shared__ __align__(16) ushort_t lA[2][16384];  // 2 K-regions x (16 kl x 2 m x 64 pos) bf16x8
    __shared__ __align__(16) float    lZp[2][4608];  // 2 partials x [col 128][row 32] pad 36

    const int tid = threadIdx.x, w = tid >> 6, lane = tid & 63;
    const int id = blockIdx.x;
    const int g  = id & 7;           // batch-row group (self-contained scan)
    const int s  = id >> 3;          // 0..31: h-col tile within group
    const int r0 = g << 5;           // 32 batch rows
    const int hb = s << 5;           // 32 h cols
    int* const barw = &bar[g << 5];  // group arrival counter
    const int kw = w >> 1, nw = w & 1;

    // ---- B-fragments: Brg[gate][kl], kl = K32 index within this wave's K-span ----
    bf16x8 Brg[4][16];
    #pragma unroll
    for (int G = 0; G < 4; ++G) {
        const int gnt = (((s << 1) + nw) << 2) + G;      // global ntile
        const ushort_t* bp = Msum + (((size_t)(gnt << 5) + (kw << 4)) << 9) + (lane << 3);
        #pragma unroll
        for (int kl = 0; kl < 16; ++kl)
            Brg[G][kl] = *(const bf16x8*)(bp + ((size_t)kl << 9));
    }

    // ---- c-state + bias in registers: thread owns row=tid>>3, cols gu4..gu4+3 ----
    const int grow = tid >> 3, gu4 = (tid & 7) << 2;
    float c_reg[4], bi[4], bfv[4], bgv[4], bo[4];
    #pragma unroll
    for (int j = 0; j < 4; ++j) {
        int u = gu4 + j;
        c_reg[j] = cin[(size_t)(r0 + grow) * Hh + hb + u];
        bi[j]  = bias[       hb + u];
        bfv[j] = bias[1024 + hb + u];
        bgv[j] = bias[2048 + hb + u];
        bo[j]  = bias[3072 + hb + u];
    }

    // staging: wave (kw,nw) stages rows [16nw,16nw+16) x k [512kw,512kw+512):
    // lane holds k-piece (lane*8) of each row i; kl_s = lane>>2, q_s = lane&3
    const int kl_s = lane >> 2, q_s = lane & 3;
    const size_t gbase = (size_t)(r0 + (nw << 4)) * Hh + (kw << 9) + (lane << 3);
    const int qq = lane >> 4, mml = lane & 15;

    #pragma unroll 1
    for (int t = 1; t < Tt; ++t) {
        const ushort_t* Ap = seq + ((size_t)(t - 1) << 18) + gbase;

        // ---- stage own slice (two batches of 8 to bound reg pressure) ----
        #pragma unroll
        for (int half = 0; half < 2; ++half) {
            bf16x8 rA[8];
            #pragma unroll
            for (int i = 0; i < 8; ++i)
                rA[i] = *(const bf16x8*)(Ap + ((size_t)((half << 3) + i) << 10));
            #pragma unroll
            for (int i = 0; i < 8; ++i) {
                int mm = (half << 3) + i;
                int pos = (q_s << 4) | (mm ^ (((kl_s << 2) + q_s) & 15));
                *(bf16x8*)&lA[kw][((((kl_s << 1) + nw) << 6) | pos) << 3] = rA[i];
            }
        }
        __syncthreads();   // partner wave's row-half staged

        // ---- MFMA: full 32x128 Z partial over this wave's K-span ----
        f32x4 acc[2][4];
        #pragma unroll
        for (int m = 0; m < 2; ++m)
            #pragma unroll
            for (int G = 0; G < 4; ++G) acc[m][G] = (f32x4){0.f, 0.f, 0.f, 0.f};

        #pragma unroll
        for (int kl = 0; kl < 16; ++kl) {
            const int pos = (qq << 4) | (mml ^ (((kl << 2) + qq) & 15));
            bf16x8 af0 = *(const bf16x8*)&lA[kw][((((kl << 1) + 0) << 6) | pos) << 3];
            bf16x8 af1 = *(const bf16x8*)&lA[kw][((((kl << 1) + 1) << 6) | pos) << 3];
            #pragma unroll
            for (int G = 0; G < 4; ++G) {
                acc[0][G] = __builtin_amdgcn_mfma_f32_16x16x32_bf16(af0, Brg[G][kl], acc[0][G], 0, 0, 0);
                acc[1][G] = __builtin_amdgcn_mfma_f32_16x16x32_bf16(af1, Brg[G][kl], acc[1][G], 0, 0, 0);
            }
        }

        // ---- Z partial write: col-major [col][row], pad 36, b128 per tile ----
        #pragma unroll
        for (int m = 0; m < 2; ++m)
            #pragma unroll
            for (int G = 0; G < 4; ++G) {
                int col = (nw << 6) + (G << 4) + mml;
                *(f32x4*)&lZp[kw][col * 36 + (m << 4) + (qq << 2)] = acc[m][G];
            }
        __syncthreads();

        // ---- 2-partial reduce + gates + publish (one 8B agent exchange) ----
        {
            unsigned long long pk = 0;
            #pragma unroll
            for (int j = 0; j < 4; ++j) {
                int u = gu4 + j;
                int cb = ((u >> 4) << 6) + (u & 15);
                float zi = lZp[0][(cb     ) * 36 + grow] + lZp[1][(cb     ) * 36 + grow] + bi[j];
                float zf = lZp[0][(cb + 16) * 36 + grow] + lZp[1][(cb + 16) * 36 + grow] + bfv[j];
                float zg = lZp[0][(cb + 32) * 36 + grow] + lZp[1][(cb + 32) * 36 + grow] + bgv[j];
                float zo = lZp[0][(cb + 48) * 36 + grow] + lZp[1][(cb + 48) * 36 + grow] + bo[j];
                float cn = sigf(zf) * c_reg[j] + sigf(zi) * tanhf_(zg);
                c_reg[j] = cn;
                pk |= (unsigned long long)f2bf(sigf(zo) * tanhf_(cn)) << (j << 4);
            }
            __hip_atomic_exchange(
                (unsigned long long*)&seq[((size_t)t << 18) +
                                          (size_t)(r0 + grow) * Hh + hb + gu4],
                pk, __ATOMIC_RELAXED, __HIP_MEMORY_SCOPE_AGENT);
        }

        if (t < Tt - 1) {
            __syncthreads();   // drains vmcnt: exchanges acked at the coherent point
            if (tid == 0) {
                __hip_atomic_fetch_add(barw, 1, __ATOMIC_RELAXED,
                                       __HIP_MEMORY_SCOPE_AGENT);
                int guard = 0;
                while (__hip_atomic_fetch_add(barw, 0, __ATOMIC_RELAXED,
                                              __HIP_MEMORY_SCOPE_AGENT) < (t << 5)
                       && ++guard < 30000)
                    __builtin_amdgcn_s_sleep(1);
            }
            __syncthreads();
        }
    }
}

// ---------- batched emission, XCD-pinned, XOR-swizzled A staging ----------
__global__ __launch_bounds__(256) void emit(
    const ushort_t* __restrict__ seq,
    const ushort_t* __restrict__ Wsw,
    const float* __restrict__ bd,
    float* __restrict__ out)
{
    __shared__ __align__(16) ushort_t lA[2 * 8 * 64 * 8];
    __shared__ __align__(16) ushort_t lB[2 * 8 * 64 * 8];
    const int tid = threadIdx.x, w = tid >> 6, lane = tid & 63;
    const int id = blockIdx.x;
    const int rt = ((id >> 5) << 3) | (id & 7);
    const int ct = (id >> 3) & 3;
    const int r0 = rt << 7, f0 = ct << 7;
    const int wr = w >> 1, wc = w & 1;

    f32x4 acc[4][4];
    #pragma unroll
    for (int m = 0; m < 4; ++m)
        #pragma unroll
        for (int n = 0; n < 4; ++n) acc[m][n] = (f32x4){0.f, 0.f, 0.f, 0.f};

    for (int kc = 0; kc < Hh; kc += 64) {
        #pragma unroll
        for (int i = 0; i < 4; ++i) {
            int p = (i << 8) + tid;
            int row = p >> 3, kpp = p & 7;
            bf16x8 v = *(const bf16x8*)(seq + (size_t)(r0 + row) * Hh + kc + (kpp << 3));
            int kk = kpp >> 2, q = kpp & 3, msub = row >> 4, mm = row & 15;
            int pos = (q << 4) | (mm ^ (((kk << 2) + q) & 15));
            *(bf16x8*)&lA[((((kk << 3) + msub) << 6) + pos) << 3] = v;
        }
        #pragma unroll
        for (int i = 0; i < 4; ++i) {
            int d = (i << 8) + tid;
            int kk = d >> 9, csub = (d >> 6) & 7, ln = d & 63;
            int nt = (ct << 3) + csub;
            bf16x8 v = *(const bf16x8*)(Wsw + (((size_t)(nt * 32 + (kc >> 5) + kk)) << 9) + (ln << 3));
            *(bf16x8*)&lB[d << 3] = v;
        }
        __syncthreads();
        const int qq = lane >> 4, mm = lane & 15;
        #pragma unroll
        for (int kk = 0; kk < 2; ++kk) {
            const int pos = (qq << 4) | (mm ^ (((kk << 2) + qq) & 15));
            bf16x8 af[4], bfr[4];
            #pragma unroll
            for (int m = 0; m < 4; ++m)
                af[m] = *(const bf16x8*)&lA[((((kk << 3) + (wr << 2) + m) << 6) + pos) << 3];
            #pragma unroll
            for (int n = 0; n < 4; ++n)
                bfr[n] = *(const bf16x8*)&lB[((((kk << 3) + (wc << 2) + n) << 6) + lane) << 3];
            #pragma unroll
            for (int m = 0; m < 4; ++m)
                #pragma unroll
                for (int n = 0; n < 4; ++n)
                    acc[m][n] = __builtin_amdgcn_mfma_f32_16x16x32_bf16(
                        af[m], bfr[n], acc[m][n], 0, 0, 0);
        }
        __syncthreads();
    }

    int q = lane >> 4, nl = lane & 15;
    float bdv[4];
    #pragma unroll
    for (int n = 0; n < 4; ++n) bdv[n] = bd[f0 + (wc << 6) + (n << 4) + nl];
    #pragma unroll
    for (int m = 0; m < 4; ++m)
        #pragma unroll
        for (int r = 0; r < 4; ++r) {
            int grow2 = r0 + (wr << 6) + (m << 4) + (q << 2) + r;  // = t*256 + b
            int tt = grow2 >> 8, bb = grow2 & 255;
            float* op = out + ((size_t)((bb << 7) + tt) << 9);
            #pragma unroll
            for (int n = 0; n < 4; ++n)
                op[f0 + (wc << 6) + (n << 4) + nl] = acc[m][n][r] + bdv[n];
        }
}

// ---------- launch ----------
extern "C" void kernel_launch(void* const* d_in, const int* in_sizes, int n_in,
                              void* d_out, int out_size, void* d_ws, size_t ws_size,
                              hipStream_t stream)
{
    const float* x0 = (const float*)d_in[0];
    const float* h0 = (const float*)d_in[1];
    const float* c0 = (const float*)d_in[2];
    const float* W  = (const float*)d_in[3];
    const float* U  = (const float*)d_in[4];
    const float* b  = (const float*)d_in[5];
    const float* Wd = (const float*)d_in[6];
    const float* bd = (const float*)d_in[7];
    float* out = (float*)d_out;

    const size_t OFF_MCAT = 0;                  // 16,777,216
    const size_t OFF_MSUM = 16777216;           //  8,388,608
    const size_t OFF_WSW  = 25165824;           //  1,048,576
    const size_t OFF_A0   = 26214400;           //  1,048,576
    const size_t OFF_SEQ  = 27262976;           // 67,108,864
    const size_t OFF_BAR  = 94371840;           //      4,096
    const size_t WS_NEED  = 94375936;
    if (ws_size < WS_NEED) return;

    char* ws = (char*)d_ws;
    ushort_t* Mcat = (ushort_t*)(ws + OFF_MCAT);
    ushort_t* Msum = (ushort_t*)(ws + OFF_MSUM);
    ushort_t* Wsw  = (ushort_t*)(ws + OFF_WSW);
    ushort_t* A0   = (ushort_t*)(ws + OFF_A0);
    ushort_t* seq  = (ushort_t*)(ws + OFF_SEQ);
    int*      bar  = (int*)(ws + OFF_BAR);
    float* cws = out;   // c-state scratch: dead before emit overwrites out

    zero_bar<<<4, 256, 0, stream>>>(bar);
    mk_a0<<<2048, 256, 0, stream>>>(x0, h0, A0);
    swz<<<4096, 256, 0, stream>>>(W, U, Mcat, 2048, 4096, 1, 2048 * 4096);
    swz<<<2048, 256, 0, stream>>>(W, U, Msum, 1024, 4096, 0, 1024 * 4096);
    swz<<<512, 256, 0, stream>>>(Wd, nullptr, Wsw, 1024, 512, 2, 1024 * 512);

    lstm_step<<<256, 256, 0, stream>>>(A0, 2048, Mcat, c0, cws, seq, b);
    lstm_scan<<<256, 256, 0, stream>>>(seq, Msum, b, cws, bar);

    emit<<<1024, 256, 0, stream>>>(seq, Wsw, bd, out);
}

// Round 6
// 838.919 us; speedup vs baseline: 1.3919x; 1.3919x over previous
//
#include <hip/hip_runtime.h>
#include <cstddef>
#include <cstdint>

typedef unsigned short ushort_t;
typedef __attribute__((ext_vector_type(8))) short bf16x8;
typedef __attribute__((ext_vector_type(4))) float f32x4;

#define Bb 256
#define Hh 1024
#define Ff 512
#define Tt 128

// ---------- helpers ----------
__device__ __forceinline__ ushort_t f2bf(float f) {
    unsigned int u = __float_as_uint(f);
    unsigned int r = (u + 0x7FFFu + ((u >> 16) & 1u)) >> 16;
    return (ushort_t)r;
}
__device__ __forceinline__ float sigf(float x)  { return 1.0f / (1.0f + __expf(-x)); }
__device__ __forceinline__ float tanhf_(float x){ return 2.0f / (1.0f + __expf(-2.0f * x)) - 1.0f; }

// ---------- weight swizzle: row-major fp32 [K][N] -> bf16 B-fragment blocks ----------
// 1KB blocks [ntile][kstep]; within: lane=(koff/8)*16+(n%16), j=koff%8.
// modes 0/1: gate-interleaved ntile = ugroup*4 + gate. mode 2 (Wd): plain.
__global__ void swz(const float* __restrict__ s0, const float* __restrict__ s1,
                    ushort_t* __restrict__ dst, int K, int N, int mode, int total)
{
    int KB = K >> 5;
    for (int idx = blockIdx.x * blockDim.x + threadIdx.x; idx < total;
         idx += gridDim.x * blockDim.x) {
        int blk   = idx >> 9;
        int lane  = (idx >> 3) & 63;
        int j     = idx & 7;
        int ntile = blk / KB;
        int kstep = blk - ntile * KB;
        int k = (kstep << 5) + ((lane >> 4) << 3) + j;
        int n;
        if (mode == 2) n = (ntile << 4) + (lane & 15);
        else           n = ((ntile & 3) << 10) + ((ntile >> 2) << 4) + (lane & 15);
        float v;
        if (mode == 0)      v = s0[(size_t)k * N + n] + s1[(size_t)k * N + n];
        else if (mode == 1) v = (k < 1024) ? s0[(size_t)k * N + n]
                                           : s1[(size_t)(k - 1024) * N + n];
        else                v = s0[(size_t)k * N + n];
        dst[idx] = f2bf(v);
    }
}

// ---------- A0 = [x0 | h0] as bf16, row-major [256][2048] ----------
__global__ void mk_a0(const float* __restrict__ x0, const float* __restrict__ h0,
                      ushort_t* __restrict__ a0)
{
    int idx = blockIdx.x * blockDim.x + threadIdx.x;
    if (idx >= Bb * 2048) return;
    int r = idx >> 11, k = idx & 2047;
    float v = (k < 1024) ? x0[r * 1024 + k] : h0[r * 1024 + k - 1024];
    a0[idx] = f2bf(v);
}

__global__ void zero_bar(int* bar) {
    int i = blockIdx.x * blockDim.x + threadIdx.x;
    if (i < 1024) bar[i] = 0;
}

// bar layout (ints, 128B-spaced lines):
//   bar[g*32] : arrival counter for logical group g = blockIdx&7 (32 blocks).
//   All ops agent-scope RMW -> execute at the coherent point (LLC): converges
//   for ANY block->XCD placement (proven r4).

// ---------- step 0 (K=2048, Mcat streamed): round-2 kernel, proven ----------
__global__ __launch_bounds__(256) void lstm_step(
    const ushort_t* __restrict__ Ap, int K,
    const ushort_t* __restrict__ Bw,
    const float* cin, float* cout,
    ushort_t* __restrict__ seqt,
    const float* __restrict__ bias)
{
    __shared__ __align__(16) ushort_t lA[32 * 512];
    __shared__ __align__(16) ushort_t lB[32 * 512];

    const int tid = threadIdx.x, w = tid >> 6, lane = tid & 63;
    const int id = blockIdx.x;
    const int ntg = ((id & 7) << 3) | (id >> 5);
    const int bt  = (id >> 3) & 3;
    const int r0 = bt << 6, hb = ntg << 4;
    const int wr = w >> 1, wc = w & 1;
    const int KB = K >> 5;

    f32x4 acc[2][2];
    #pragma unroll
    for (int m = 0; m < 2; ++m)
        #pragma unroll
        for (int n = 0; n < 2; ++n) acc[m][n] = (f32x4){0.f, 0.f, 0.f, 0.f};

    const int kp = tid & 31;
    const int q_a = kp & 3, kk_a = kp >> 2;

    for (int kc = 0; kc < K; kc += 256) {
        bf16x8 va[8];
        #pragma unroll
        for (int i = 0; i < 8; ++i) {
            int row = (i << 3) + (tid >> 5);
            va[i] = *(const bf16x8*)(Ap + (size_t)(r0 + row) * K + kc + (kp << 3));
        }
        bf16x8 vb[8];
        #pragma unroll
        for (int i = 0; i < 8; ++i)
            vb[i] = *(const bf16x8*)(Bw +
                ((((size_t)((ntg << 2) + w)) * KB + (kc >> 5) + i) << 9) + (lane << 3));
        #pragma unroll
        for (int i = 0; i < 8; ++i) {
            int row = (i << 3) + (tid >> 5);
            int msub = row >> 4, mm = row & 15;
            int pos = (q_a << 4) | (mm ^ (((kk_a << 2) + q_a) & 15));
            *(bf16x8*)&lA[((((kk_a << 2) + msub) << 6) + pos) << 3] = va[i];
        }
        #pragma unroll
        for (int i = 0; i < 8; ++i)
            *(bf16x8*)&lB[(((i << 2) + w) << 9) + (lane << 3)] = vb[i];
        __syncthreads();

        #pragma unroll
        for (int kk = 0; kk < 8; ++kk) {
            const int qq = lane >> 4, mm = lane & 15;
            const int pos = (qq << 4) | (mm ^ (((kk << 2) + qq) & 15));
            bf16x8 af[2], bfr[2];
            #pragma unroll
            for (int m = 0; m < 2; ++m)
                af[m] = *(const bf16x8*)&lA[((((kk << 2) + (wr << 1) + m) << 6) + pos) << 3];
            #pragma unroll
            for (int n = 0; n < 2; ++n)
                bfr[n] = *(const bf16x8*)&lB[((((kk << 2) + (wc << 1) + n) << 6) + lane) << 3];
            #pragma unroll
            for (int m = 0; m < 2; ++m)
                #pragma unroll
                for (int n = 0; n < 2; ++n)
                    acc[m][n] = __builtin_amdgcn_mfma_f32_16x16x32_bf16(
                        af[m], bfr[n], acc[m][n], 0, 0, 0);
        }
        __syncthreads();
    }

    float* lZ = (float*)lA;
    {
        int q = lane >> 4, nl = lane & 15;
        #pragma unroll
        for (int m = 0; m < 2; ++m)
            #pragma unroll
            for (int n = 0; n < 2; ++n)
                #pragma unroll
                for (int r = 0; r < 4; ++r)
                    lZ[((wr << 5) + (m << 4) + (q << 2) + r) * 68 +
                       (wc << 5) + (n << 4) + nl] = acc[m][n][r];
    }
    __syncthreads();

    #pragma unroll
    for (int i = 0; i < 4; ++i) {
        int idx = (i << 8) + tid;
        int row = idx >> 4, u = idx & 15;
        float zi = lZ[row * 68 +      u] + bias[       hb + u];
        float zf = lZ[row * 68 + 16 + u] + bias[1024 + hb + u];
        float zg = lZ[row * 68 + 32 + u] + bias[2048 + hb + u];
        float zo = lZ[row * 68 + 48 + u] + bias[3072 + hb + u];
        size_t cidx = (size_t)(r0 + row) * Hh + hb + u;
        float cp = cin[cidx];
        float cn = sigf(zf) * cp + sigf(zi) * tanhf_(zg);
        cout[cidx] = cn;
        seqt[cidx] = f2bf(sigf(zo) * tanhf_(cn));
    }
}

// ---------- persistent scan, steps 1..127 — r4 structure + PINNED B registers ----------
// Group g = id&7 owns rows [32g,32g+32); block s = id>>3 owns h-cols [32s,32s+32)
// (Z tile 32x128). r4's proven pipeline (per-kc stage/load overlap with MFMA),
// publish via relaxed agent-scope 8B atomic exchange, per-group barrier of
// agent-scope RMW arrival+poll. ONE change vs r4: Brg fragments are pinned in
// VGPRs via empty asm (r4's VGPR_Count=184 proved the compiler re-loaded all
// 64 B-frags from L2 every step: 8 MB/XCD/step ~= 1.8us of the 5.25us step).
// Budget ~360 VGPR < 512 allowed at launch_bounds(256,1); occupancy already
// 1 block/CU so the bigger allocation is free.
__global__ __launch_bounds__(256, 1) void lstm_scan(
    ushort_t* __restrict__ seq,
    const ushort_t* __restrict__ Msum,
    const float* __restrict__ bias,
    const float* __restrict__ cin,
    int* __restrict__ bar)
{
    __shared__ __align__(16) ushort_t lA[2][4096];   // 2 x 8KB A chunks (32 rows x 128 k)

    const int tid = threadIdx.x, w = tid >> 6, lane = tid & 63;
    const int id = blockIdx.x;
    const int g  = id & 7;           // batch-row group (self-contained scan)
    const int s  = id >> 3;          // 0..31: h-col tile within group
    const int r0 = g << 5;           // 32 batch rows
    const int hb = s << 5;           // 32 h cols
    int* const barw = &bar[g << 5];  // group arrival counter (one line per group)

    // ---- resident B in registers: wave w holds ntl = 2w, 2w+1; PINNED ----
    // ntl -> (ul = ntl>>2, gate = ntl&3); global ntile = (2s+ul)*4+gate
    bf16x8 Brg[2][32];
    #pragma unroll
    for (int n = 0; n < 2; ++n) {
        const int ntl = (w << 1) + n;
        const int gnt = (((s << 1) + (ntl >> 2)) << 2) + (ntl & 3);
        const ushort_t* bp = Msum + (((size_t)gnt << 5) << 9) + (lane << 3);
        #pragma unroll
        for (int ks = 0; ks < 32; ++ks) {
            Brg[n][ks] = *(const bf16x8*)(bp + ((size_t)ks << 9));
            // pin: opaque asm output -> cannot be rematerialized from the load;
            // value must stay live in VGPRs across the whole t-loop
            asm volatile("" : "+v"(Brg[n][ks]));
        }
    }

    // ---- c-state + bias in registers: thread owns row=tid>>3, cols gu4..gu4+3 ----
    const int grow = tid >> 3, gu4 = (tid & 7) << 2;
    float c_reg[4], bi[4], bfv[4], bgv[4], bo[4];
    #pragma unroll
    for (int j = 0; j < 4; ++j) {
        int u = gu4 + j;
        c_reg[j] = cin[(size_t)(r0 + grow) * Hh + hb + u];
        bi[j]  = bias[       hb + u];
        bfv[j] = bias[1024 + hb + u];
        bgv[j] = bias[2048 + hb + u];
        bo[j]  = bias[3072 + hb + u];
    }

    float* lZ = (float*)lA;   // 32 x 128 f32 overlay (16KB)

    // A staging geometry: piece p = i*256+tid (i=0,1): row = i*16 + (tid>>4), kp = tid&15
    const int kp  = tid & 15;
    const int q_a = kp & 3, kk_a = kp >> 2;
    const int mm_s  = tid >> 4;
    const int pos_s = (q_a << 4) | (mm_s ^ (((kk_a << 2) + q_a) & 15));
    const int lw0   = (((kk_a << 1) << 6) | pos_s) << 3;      // ushort idx; piece i adds 512
    const size_t ga0 = (size_t)(r0 + mm_s) * Hh + (kp << 3);  // global base; piece i adds 1<<14

    #pragma unroll 1
    for (int t = 1; t < Tt; ++t) {
        const ushort_t* Ap = seq + ((size_t)(t - 1) << 18) + ga0;

        f32x4 acc[2][2];
        #pragma unroll
        for (int m = 0; m < 2; ++m)
            #pragma unroll
            for (int n = 0; n < 2; ++n) acc[m][n] = (f32x4){0.f, 0.f, 0.f, 0.f};

        bf16x8 rA[2][2];
        // prologue: chunk0 -> rA[0] -> lA[0]; chunk1 -> rA[1]
        #pragma unroll
        for (int i = 0; i < 2; ++i)
            rA[0][i] = *(const bf16x8*)(Ap + (i << 14));
        #pragma unroll
        for (int i = 0; i < 2; ++i)
            *(bf16x8*)&lA[0][lw0 + (i << 9)] = rA[0][i];
        #pragma unroll
        for (int i = 0; i < 2; ++i)
            rA[1][i] = *(const bf16x8*)(Ap + (i << 14) + 128);
        __syncthreads();

        #pragma unroll   // full unroll: Brg indices must be static (reg residency)
        for (int kc = 0; kc < 8; ++kc) {
            if (kc < 7) {   // stage chunk kc+1
                const int sb = (kc + 1) & 1;
                #pragma unroll
                for (int i = 0; i < 2; ++i)
                    *(bf16x8*)&lA[sb][lw0 + (i << 9)] = rA[sb][i];
            }
            if (kc < 6) {   // issue loads for chunk kc+2
                const int sb = kc & 1;
                #pragma unroll
                for (int i = 0; i < 2; ++i)
                    rA[sb][i] = *(const bf16x8*)(Ap + (i << 14) + ((kc + 2) << 7));
            }
            const ushort_t* lAc = lA[kc & 1];
            const int qq = lane >> 4, mr = lane & 15;
            #pragma unroll
            for (int kk = 0; kk < 4; ++kk) {
                const int pos = (qq << 4) | (mr ^ (((kk << 2) + qq) & 15));
                const int ks = (kc << 2) + kk;
                bf16x8 af0 = *(const bf16x8*)&lAc[((((kk << 1) + 0) << 6) | pos) << 3];
                bf16x8 af1 = *(const bf16x8*)&lAc[((((kk << 1) + 1) << 6) | pos) << 3];
                acc[0][0] = __builtin_amdgcn_mfma_f32_16x16x32_bf16(af0, Brg[0][ks], acc[0][0], 0, 0, 0);
                acc[0][1] = __builtin_amdgcn_mfma_f32_16x16x32_bf16(af0, Brg[1][ks], acc[0][1], 0, 0, 0);
                acc[1][0] = __builtin_amdgcn_mfma_f32_16x16x32_bf16(af1, Brg[0][ks], acc[1][0], 0, 0, 0);
                acc[1][1] = __builtin_amdgcn_mfma_f32_16x16x32_bf16(af1, Brg[1][ks], acc[1][1], 0, 0, 0);
            }
            __syncthreads();
        }

        // Z exchange into lZ (overlays lA), skew col+(5*row) -> <=2-way conflicts
        {
            const int q = lane >> 4, nl = lane & 15;
            #pragma unroll
            for (int m = 0; m < 2; ++m)
                #pragma unroll
                for (int n = 0; n < 2; ++n)
                    #pragma unroll
                    for (int r = 0; r < 4; ++r) {
                        int row = (m << 4) + (q << 2) + r;
                        int col = (((w << 1) + n) << 4) + nl;
                        lZ[(row << 7) + ((col + row * 5) & 127)] = acc[m][n][r];
                    }
        }
        __syncthreads();

        // gates + c/h update; h published via ONE relaxed agent-scope 8B atomic
        // exchange per thread (RMW lands at LLC -> visible to any consumer XCD)
        {
            const int rb5 = grow * 5;
            unsigned long long pk = 0;
            #pragma unroll
            for (int j = 0; j < 4; ++j) {
                int u = gu4 + j;
                int cb = ((u >> 4) << 6) + (u & 15);   // gate-0 Z col for this h col
                float zi = lZ[(grow << 7) + ((cb      + rb5) & 127)] + bi[j];
                float zf = lZ[(grow << 7) + ((cb + 16 + rb5) & 127)] + bfv[j];
                float zg = lZ[(grow << 7) + ((cb + 32 + rb5) & 127)] + bgv[j];
                float zo = lZ[(grow << 7) + ((cb + 48 + rb5) & 127)] + bo[j];
                float cn = sigf(zf) * c_reg[j] + sigf(zi) * tanhf_(zg);
                c_reg[j] = cn;
                pk |= (unsigned long long)f2bf(sigf(zo) * tanhf_(cn)) << (j << 4);
            }
            __hip_atomic_exchange(
                (unsigned long long*)&seq[((size_t)t << 18) +
                                          (size_t)(r0 + grow) * Hh + hb + gu4],
                pk, __ATOMIC_RELAXED, __HIP_MEMORY_SCOPE_AGENT);
        }

        if (t < Tt - 1) {
            __syncthreads();   // drains vmcnt: exchanges acked at the coherent point
            if (tid == 0) {
                // per-group barrier: agent-scope RMW arrival + RMW poll on one
                // LLC line (32 writers); no cross-group coupling
                __hip_atomic_fetch_add(barw, 1, __ATOMIC_RELAXED,
                                       __HIP_MEMORY_SCOPE_AGENT);
                int guard = 0;
                while (__hip_atomic_fetch_add(barw, 0, __ATOMIC_RELAXED,
                                              __HIP_MEMORY_SCOPE_AGENT) < (t << 5)
                       && ++guard < 30000)
                    __builtin_amdgcn_s_sleep(2);
            }
            __syncthreads();
        }
    }
}

// ---------- batched emission, XCD-pinned, XOR-swizzled A staging ----------
__global__ __launch_bounds__(256) void emit(
    const ushort_t* __restrict__ seq,
    const ushort_t* __restrict__ Wsw,
    const float* __restrict__ bd,
    float* __restrict__ out)
{
    __shared__ __align__(16) ushort_t lA[2 * 8 * 64 * 8];
    __shared__ __align__(16) ushort_t lB[2 * 8 * 64 * 8];
    const int tid = threadIdx.x, w = tid >> 6, lane = tid & 63;
    const int id = blockIdx.x;
    const int rt = ((id >> 5) << 3) | (id & 7);
    const int ct = (id >> 3) & 3;
    const int r0 = rt << 7, f0 = ct << 7;
    const int wr = w >> 1, wc = w & 1;

    f32x4 acc[4][4];
    #pragma unroll
    for (int m = 0; m < 4; ++m)
        #pragma unroll
        for (int n = 0; n < 4; ++n) acc[m][n] = (f32x4){0.f, 0.f, 0.f, 0.f};

    for (int kc = 0; kc < Hh; kc += 64) {
        #pragma unroll
        for (int i = 0; i < 4; ++i) {
            int p = (i << 8) + tid;
            int row = p >> 3, kpp = p & 7;
            bf16x8 v = *(const bf16x8*)(seq + (size_t)(r0 + row) * Hh + kc + (kpp << 3));
            int kk = kpp >> 2, q = kpp & 3, msub = row >> 4, mm = row & 15;
            int pos = (q << 4) | (mm ^ (((kk << 2) + q) & 15));
            *(bf16x8*)&lA[((((kk << 3) + msub) << 6) + pos) << 3] = v;
        }
        #pragma unroll
        for (int i = 0; i < 4; ++i) {
            int d = (i << 8) + tid;
            int kk = d >> 9, csub = (d >> 6) & 7, ln = d & 63;
            int nt = (ct << 3) + csub;
            bf16x8 v = *(const bf16x8*)(Wsw + (((size_t)(nt * 32 + (kc >> 5) + kk)) << 9) + (ln << 3));
            *(bf16x8*)&lB[d << 3] = v;
        }
        __syncthreads();
        const int qq = lane >> 4, mm = lane & 15;
        #pragma unroll
        for (int kk = 0; kk < 2; ++kk) {
            const int pos = (qq << 4) | (mm ^ (((kk << 2) + qq) & 15));
            bf16x8 af[4], bfr[4];
            #pragma unroll
            for (int m = 0; m < 4; ++m)
                af[m] = *(const bf16x8*)&lA[((((kk << 3) + (wr << 2) + m) << 6) + pos) << 3];
            #pragma unroll
            for (int n = 0; n < 4; ++n)
                bfr[n] = *(const bf16x8*)&lB[((((kk << 3) + (wc << 2) + n) << 6) + lane) << 3];
            #pragma unroll
            for (int m = 0; m < 4; ++m)
                #pragma unroll
                for (int n = 0; n < 4; ++n)
                    acc[m][n] = __builtin_amdgcn_mfma_f32_16x16x32_bf16(
                        af[m], bfr[n], acc[m][n], 0, 0, 0);
        }
        __syncthreads();
    }

    int q = lane >> 4, nl = lane & 15;
    float bdv[4];
    #pragma unroll
    for (int n = 0; n < 4; ++n) bdv[n] = bd[f0 + (wc << 6) + (n << 4) + nl];
    #pragma unroll
    for (int m = 0; m < 4; ++m)
        #pragma unroll
        for (int r = 0; r < 4; ++r) {
            int grow2 = r0 + (wr << 6) + (m << 4) + (q << 2) + r;  // = t*256 + b
            int tt = grow2 >> 8, bb = grow2 & 255;
            float* op = out + ((size_t)((bb << 7) + tt) << 9);
            #pragma unroll
            for (int n = 0; n < 4; ++n)
                op[f0 + (wc << 6) + (n << 4) + nl] = acc[m][n][r] + bdv[n];
        }
}

// ---------- launch ----------
extern "C" void kernel_launch(void* const* d_in, const int* in_sizes, int n_in,
                              void* d_out, int out_size, void* d_ws, size_t ws_size,
                              hipStream_t stream)
{
    const float* x0 = (const float*)d_in[0];
    const float* h0 = (const float*)d_in[1];
    const float* c0 = (const float*)d_in[2];
    const float* W  = (const float*)d_in[3];
    const float* U  = (const float*)d_in[4];
    const float* b  = (const float*)d_in[5];
    const float* Wd = (const float*)d_in[6];
    const float* bd = (const float*)d_in[7];
    float* out = (float*)d_out;

    const size_t OFF_MCAT = 0;                  // 16,777,216
    const size_t OFF_MSUM = 16777216;           //  8,388,608
    const size_t OFF_WSW  = 25165824;           //  1,048,576
    const size_t OFF_A0   = 26214400;           //  1,048,576
    const size_t OFF_SEQ  = 27262976;           // 67,108,864
    const size_t OFF_BAR  = 94371840;           //      4,096
    const size_t WS_NEED  = 94375936;
    if (ws_size < WS_NEED) return;

    char* ws = (char*)d_ws;
    ushort_t* Mcat = (ushort_t*)(ws + OFF_MCAT);
    ushort_t* Msum = (ushort_t*)(ws + OFF_MSUM);
    ushort_t* Wsw  = (ushort_t*)(ws + OFF_WSW);
    ushort_t* A0   = (ushort_t*)(ws + OFF_A0);
    ushort_t* seq  = (ushort_t*)(ws + OFF_SEQ);
    int*      bar  = (int*)(ws + OFF_BAR);
    float* cws = out;   // c-state scratch: dead before emit overwrites out

    zero_bar<<<4, 256, 0, stream>>>(bar);
    mk_a0<<<2048, 256, 0, stream>>>(x0, h0, A0);
    swz<<<4096, 256, 0, stream>>>(W, U, Mcat, 2048, 4096, 1, 2048 * 4096);
    swz<<<2048, 256, 0, stream>>>(W, U, Msum, 1024, 4096, 0, 1024 * 4096);
    swz<<<512, 256, 0, stream>>>(Wd, nullptr, Wsw, 1024, 512, 2, 1024 * 512);

    lstm_step<<<256, 256, 0, stream>>>(A0, 2048, Mcat, c0, cws, seq, b);
    lstm_scan<<<256, 256, 0, stream>>>(seq, Msum, b, cws, bar);

    emit<<<1024, 256, 0, stream>>>(seq, Wsw, bd, out);
}

// Round 7
// 828.272 us; speedup vs baseline: 1.4098x; 1.0129x over previous
//
#include <hip/hip_runtime.h>
#include <cstddef>
#include <cstdint>

typedef unsigned short ushort_t;
typedef __attribute__((ext_vector_type(8))) short bf16x8;
typedef __attribute__((ext_vector_type(4))) float f32x4;

#define Bb 256
#define Hh 1024
#define Ff 512
#define Tt 128

// ---------- helpers ----------
__device__ __forceinline__ ushort_t f2bf(float f) {
    unsigned int u = __float_as_uint(f);
    unsigned int r = (u + 0x7FFFu + ((u >> 16) & 1u)) >> 16;
    return (ushort_t)r;
}
__device__ __forceinline__ float sigf(float x)  { return 1.0f / (1.0f + __expf(-x)); }
__device__ __forceinline__ float tanhf_(float x){ return 2.0f / (1.0f + __expf(-2.0f * x)) - 1.0f; }

// ---------- weight swizzle: row-major fp32 [K][N] -> bf16 B-fragment blocks ----------
// 1KB blocks [ntile][kstep]; within: lane=(koff/8)*16+(n%16), j=koff%8.
// modes 0/1: gate-interleaved ntile = ugroup*4 + gate. mode 2 (Wd): plain.
__global__ void swz(const float* __restrict__ s0, const float* __restrict__ s1,
                    ushort_t* __restrict__ dst, int K, int N, int mode, int total)
{
    int KB = K >> 5;
    for (int idx = blockIdx.x * blockDim.x + threadIdx.x; idx < total;
         idx += gridDim.x * blockDim.x) {
        int blk   = idx >> 9;
        int lane  = (idx >> 3) & 63;
        int j     = idx & 7;
        int ntile = blk / KB;
        int kstep = blk - ntile * KB;
        int k = (kstep << 5) + ((lane >> 4) << 3) + j;
        int n;
        if (mode == 2) n = (ntile << 4) + (lane & 15);
        else           n = ((ntile & 3) << 10) + ((ntile >> 2) << 4) + (lane & 15);
        float v;
        if (mode == 0)      v = s0[(size_t)k * N + n] + s1[(size_t)k * N + n];
        else if (mode == 1) v = (k < 1024) ? s0[(size_t)k * N + n]
                                           : s1[(size_t)(k - 1024) * N + n];
        else                v = s0[(size_t)k * N + n];
        dst[idx] = f2bf(v);
    }
}

// ---------- A0 = [x0 | h0] as bf16, row-major [256][2048] ----------
__global__ void mk_a0(const float* __restrict__ x0, const float* __restrict__ h0,
                      ushort_t* __restrict__ a0)
{
    int idx = blockIdx.x * blockDim.x + threadIdx.x;
    if (idx >= Bb * 2048) return;
    int r = idx >> 11, k = idx & 2047;
    float v = (k < 1024) ? x0[r * 1024 + k] : h0[r * 1024 + k - 1024];
    a0[idx] = f2bf(v);
}

__global__ void zero_bar(int* bar) {
    int i = blockIdx.x * blockDim.x + threadIdx.x;
    if (i < 1024) bar[i] = 0;
}

// bar layout (ints, 128B-spaced lines):
//   bar[g*32] : arrival counter for logical group g = blockIdx&7 (32 blocks).
//   All ops agent-scope RMW -> execute at the coherent point (LLC): converges
//   for ANY block->XCD placement (proven r4).

// ---------- step 0 (K=2048, Mcat streamed): round-2 kernel, proven ----------
__global__ __launch_bounds__(256) void lstm_step(
    const ushort_t* __restrict__ Ap, int K,
    const ushort_t* __restrict__ Bw,
    const float* cin, float* cout,
    ushort_t* __restrict__ seqt,
    const float* __restrict__ bias)
{
    __shared__ __align__(16) ushort_t lA[32 * 512];
    __shared__ __align__(16) ushort_t lB[32 * 512];

    const int tid = threadIdx.x, w = tid >> 6, lane = tid & 63;
    const int id = blockIdx.x;
    const int ntg = ((id & 7) << 3) | (id >> 5);
    const int bt  = (id >> 3) & 3;
    const int r0 = bt << 6, hb = ntg << 4;
    const int wr = w >> 1, wc = w & 1;
    const int KB = K >> 5;

    f32x4 acc[2][2];
    #pragma unroll
    for (int m = 0; m < 2; ++m)
        #pragma unroll
        for (int n = 0; n < 2; ++n) acc[m][n] = (f32x4){0.f, 0.f, 0.f, 0.f};

    const int kp = tid & 31;
    const int q_a = kp & 3, kk_a = kp >> 2;

    for (int kc = 0; kc < K; kc += 256) {
        bf16x8 va[8];
        #pragma unroll
        for (int i = 0; i < 8; ++i) {
            int row = (i << 3) + (tid >> 5);
            va[i] = *(const bf16x8*)(Ap + (size_t)(r0 + row) * K + kc + (kp << 3));
        }
        bf16x8 vb[8];
        #pragma unroll
        for (int i = 0; i < 8; ++i)
            vb[i] = *(const bf16x8*)(Bw +
                ((((size_t)((ntg << 2) + w)) * KB + (kc >> 5) + i) << 9) + (lane << 3));
        #pragma unroll
        for (int i = 0; i < 8; ++i) {
            int row = (i << 3) + (tid >> 5);
            int msub = row >> 4, mm = row & 15;
            int pos = (q_a << 4) | (mm ^ (((kk_a << 2) + q_a) & 15));
            *(bf16x8*)&lA[((((kk_a << 2) + msub) << 6) + pos) << 3] = va[i];
        }
        #pragma unroll
        for (int i = 0; i < 8; ++i)
            *(bf16x8*)&lB[(((i << 2) + w) << 9) + (lane << 3)] = vb[i];
        __syncthreads();

        #pragma unroll
        for (int kk = 0; kk < 8; ++kk) {
            const int qq = lane >> 4, mm = lane & 15;
            const int pos = (qq << 4) | (mm ^ (((kk << 2) + qq) & 15));
            bf16x8 af[2], bfr[2];
            #pragma unroll
            for (int m = 0; m < 2; ++m)
                af[m] = *(const bf16x8*)&lA[((((kk << 2) + (wr << 1) + m) << 6) + pos) << 3];
            #pragma unroll
            for (int n = 0; n < 2; ++n)
                bfr[n] = *(const bf16x8*)&lB[((((kk << 2) + (wc << 1) + n) << 6) + lane) << 3];
            #pragma unroll
            for (int m = 0; m < 2; ++m)
                #pragma unroll
                for (int n = 0; n < 2; ++n)
                    acc[m][n] = __builtin_amdgcn_mfma_f32_16x16x32_bf16(
                        af[m], bfr[n], acc[m][n], 0, 0, 0);
        }
        __syncthreads();
    }

    float* lZ = (float*)lA;
    {
        int q = lane >> 4, nl = lane & 15;
        #pragma unroll
        for (int m = 0; m < 2; ++m)
            #pragma unroll
            for (int n = 0; n < 2; ++n)
                #pragma unroll
                for (int r = 0; r < 4; ++r)
                    lZ[((wr << 5) + (m << 4) + (q << 2) + r) * 68 +
                       (wc << 5) + (n << 4) + nl] = acc[m][n][r];
    }
    __syncthreads();

    #pragma unroll
    for (int i = 0; i < 4; ++i) {
        int idx = (i << 8) + tid;
        int row = idx >> 4, u = idx & 15;
        float zi = lZ[row * 68 +      u] + bias[       hb + u];
        float zf = lZ[row * 68 + 16 + u] + bias[1024 + hb + u];
        float zg = lZ[row * 68 + 32 + u] + bias[2048 + hb + u];
        float zo = lZ[row * 68 + 48 + u] + bias[3072 + hb + u];
        size_t cidx = (size_t)(r0 + row) * Hh + hb + u;
        float cp = cin[cidx];
        float cn = sigf(zf) * cp + sigf(zi) * tanhf_(zg);
        cout[cidx] = cn;
        seqt[cidx] = f2bf(sigf(zo) * tanhf_(cn));
    }
}

// ---------- persistent scan, steps 1..127 — r4 structure + B pinned in AGPRs ----------
// Group g = id&7 owns rows [32g,32g+32); block s = id>>3 owns h-cols [32s,32s+32)
// (Z tile 32x128). r4's proven pipeline + publish/barrier primitives.
// ONE change vs r4/r6: Brg fragments pinned with "+a" (AGPR) constraint.
// Evidence: r4/r6 VGPR_Count=184 < 256 needed -> B was NOT resident; the "+v"
// pin (r6) changed nothing (allocator spilled to scratch = same L2 traffic:
// 64 frags x 16B/thread/step = 8MB/XCD/step ~= 1.9us of the 5.26us step).
// gfx950 MFMA reads A/B from VGPR OR AGPR (ISA §10) and the reg file is
// unified: 256 AGPR + ~184 VGPR < 512 budget at 1 wave/SIMD. AGPR "spill"
// reload is a 1-cyc v_accvgpr_read, not a memory op.
__global__ __launch_bounds__(256, 1) void lstm_scan(
    ushort_t* __restrict__ seq,
    const ushort_t* __restrict__ Msum,
    const float* __restrict__ bias,
    const float* __restrict__ cin,
    int* __restrict__ bar)
{
    __shared__ __align__(16) ushort_t lA[2][4096];   // 2 x 8KB A chunks (32 rows x 128 k)

    const int tid = threadIdx.x, w = tid >> 6, lane = tid & 63;
    const int id = blockIdx.x;
    const int g  = id & 7;           // batch-row group (self-contained scan)
    const int s  = id >> 3;          // 0..31: h-col tile within group
    const int r0 = g << 5;           // 32 batch rows
    const int hb = s << 5;           // 32 h cols
    int* const barw = &bar[g << 5];  // group arrival counter (one line per group)

    // ---- resident B: wave w holds ntl = 2w, 2w+1; PINNED IN AGPRs ----
    // ntl -> (ul = ntl>>2, gate = ntl&3); global ntile = (2s+ul)*4+gate
    bf16x8 Brg[2][32];
    #pragma unroll
    for (int n = 0; n < 2; ++n) {
        const int ntl = (w << 1) + n;
        const int gnt = (((s << 1) + (ntl >> 2)) << 2) + (ntl & 3);
        const ushort_t* bp = Msum + (((size_t)gnt << 5) << 9) + (lane << 3);
        #pragma unroll
        for (int ks = 0; ks < 32; ++ks) {
            Brg[n][ks] = *(const bf16x8*)(bp + ((size_t)ks << 9));
            // park in AGPRs: live range held in the accumulator file for the
            // whole t-loop; reload = v_accvgpr_read (1 cyc), not L2 traffic
            asm volatile("" : "+a"(Brg[n][ks]));
        }
    }

    // ---- c-state + bias in registers: thread owns row=tid>>3, cols gu4..gu4+3 ----
    const int grow = tid >> 3, gu4 = (tid & 7) << 2;
    float c_reg[4], bi[4], bfv[4], bgv[4], bo[4];
    #pragma unroll
    for (int j = 0; j < 4; ++j) {
        int u = gu4 + j;
        c_reg[j] = cin[(size_t)(r0 + grow) * Hh + hb + u];
        bi[j]  = bias[       hb + u];
        bfv[j] = bias[1024 + hb + u];
        bgv[j] = bias[2048 + hb + u];
        bo[j]  = bias[3072 + hb + u];
    }

    float* lZ = (float*)lA;   // 32 x 128 f32 overlay (16KB)

    // A staging geometry: piece p = i*256+tid (i=0,1): row = i*16 + (tid>>4), kp = tid&15
    const int kp  = tid & 15;
    const int q_a = kp & 3, kk_a = kp >> 2;
    const int mm_s  = tid >> 4;
    const int pos_s = (q_a << 4) | (mm_s ^ (((kk_a << 2) + q_a) & 15));
    const int lw0   = (((kk_a << 1) << 6) | pos_s) << 3;      // ushort idx; piece i adds 512
    const size_t ga0 = (size_t)(r0 + mm_s) * Hh + (kp << 3);  // global base; piece i adds 1<<14

    #pragma unroll 1
    for (int t = 1; t < Tt; ++t) {
        const ushort_t* Ap = seq + ((size_t)(t - 1) << 18) + ga0;

        f32x4 acc[2][2];
        #pragma unroll
        for (int m = 0; m < 2; ++m)
            #pragma unroll
            for (int n = 0; n < 2; ++n) acc[m][n] = (f32x4){0.f, 0.f, 0.f, 0.f};

        bf16x8 rA[2][2];
        // prologue: chunk0 -> rA[0] -> lA[0]; chunk1 -> rA[1]
        #pragma unroll
        for (int i = 0; i < 2; ++i)
            rA[0][i] = *(const bf16x8*)(Ap + (i << 14));
        #pragma unroll
        for (int i = 0; i < 2; ++i)
            *(bf16x8*)&lA[0][lw0 + (i << 9)] = rA[0][i];
        #pragma unroll
        for (int i = 0; i < 2; ++i)
            rA[1][i] = *(const bf16x8*)(Ap + (i << 14) + 128);
        __syncthreads();

        #pragma unroll   // full unroll: Brg indices must be static (reg residency)
        for (int kc = 0; kc < 8; ++kc) {
            if (kc < 7) {   // stage chunk kc+1
                const int sb = (kc + 1) & 1;
                #pragma unroll
                for (int i = 0; i < 2; ++i)
                    *(bf16x8*)&lA[sb][lw0 + (i << 9)] = rA[sb][i];
            }
            if (kc < 6) {   // issue loads for chunk kc+2
                const int sb = kc & 1;
                #pragma unroll
                for (int i = 0; i < 2; ++i)
                    rA[sb][i] = *(const bf16x8*)(Ap + (i << 14) + ((kc + 2) << 7));
            }
            const ushort_t* lAc = lA[kc & 1];
            const int qq = lane >> 4, mr = lane & 15;
            #pragma unroll
            for (int kk = 0; kk < 4; ++kk) {
                const int pos = (qq << 4) | (mr ^ (((kk << 2) + qq) & 15));
                const int ks = (kc << 2) + kk;
                bf16x8 af0 = *(const bf16x8*)&lAc[((((kk << 1) + 0) << 6) | pos) << 3];
                bf16x8 af1 = *(const bf16x8*)&lAc[((((kk << 1) + 1) << 6) | pos) << 3];
                acc[0][0] = __builtin_amdgcn_mfma_f32_16x16x32_bf16(af0, Brg[0][ks], acc[0][0], 0, 0, 0);
                acc[0][1] = __builtin_amdgcn_mfma_f32_16x16x32_bf16(af0, Brg[1][ks], acc[0][1], 0, 0, 0);
                acc[1][0] = __builtin_amdgcn_mfma_f32_16x16x32_bf16(af1, Brg[0][ks], acc[1][0], 0, 0, 0);
                acc[1][1] = __builtin_amdgcn_mfma_f32_16x16x32_bf16(af1, Brg[1][ks], acc[1][1], 0, 0, 0);
            }
            __syncthreads();
        }

        // Z exchange into lZ (overlays lA), skew col+(5*row) -> <=2-way conflicts
        {
            const int q = lane >> 4, nl = lane & 15;
            #pragma unroll
            for (int m = 0; m < 2; ++m)
                #pragma unroll
                for (int n = 0; n < 2; ++n)
                    #pragma unroll
                    for (int r = 0; r < 4; ++r) {
                        int row = (m << 4) + (q << 2) + r;
                        int col = (((w << 1) + n) << 4) + nl;
                        lZ[(row << 7) + ((col + row * 5) & 127)] = acc[m][n][r];
                    }
        }
        __syncthreads();

        // gates + c/h update; h published via ONE relaxed agent-scope 8B atomic
        // exchange per thread (RMW lands at LLC -> visible to any consumer XCD)
        {
            const int rb5 = grow * 5;
            unsigned long long pk = 0;
            #pragma unroll
            for (int j = 0; j < 4; ++j) {
                int u = gu4 + j;
                int cb = ((u >> 4) << 6) + (u & 15);   // gate-0 Z col for this h col
                float zi = lZ[(grow << 7) + ((cb      + rb5) & 127)] + bi[j];
                float zf = lZ[(grow << 7) + ((cb + 16 + rb5) & 127)] + bfv[j];
                float zg = lZ[(grow << 7) + ((cb + 32 + rb5) & 127)] + bgv[j];
                float zo = lZ[(grow << 7) + ((cb + 48 + rb5) & 127)] + bo[j];
                float cn = sigf(zf) * c_reg[j] + sigf(zi) * tanhf_(zg);
                c_reg[j] = cn;
                pk |= (unsigned long long)f2bf(sigf(zo) * tanhf_(cn)) << (j << 4);
            }
            __hip_atomic_exchange(
                (unsigned long long*)&seq[((size_t)t << 18) +
                                          (size_t)(r0 + grow) * Hh + hb + gu4],
                pk, __ATOMIC_RELAXED, __HIP_MEMORY_SCOPE_AGENT);
        }

        if (t < Tt - 1) {
            __syncthreads();   // drains vmcnt: exchanges acked at the coherent point
            if (tid == 0) {
                // per-group barrier: agent-scope RMW arrival + RMW poll on one
                // LLC line (32 writers); no cross-group coupling
                __hip_atomic_fetch_add(barw, 1, __ATOMIC_RELAXED,
                                       __HIP_MEMORY_SCOPE_AGENT);
                int guard = 0;
                while (__hip_atomic_fetch_add(barw, 0, __ATOMIC_RELAXED,
                                              __HIP_MEMORY_SCOPE_AGENT) < (t << 5)
                       && ++guard < 30000)
                    __builtin_amdgcn_s_sleep(2);
            }
            __syncthreads();
        }
    }
}

// ---------- batched emission, XCD-pinned, XOR-swizzled A staging ----------
__global__ __launch_bounds__(256) void emit(
    const ushort_t* __restrict__ seq,
    const ushort_t* __restrict__ Wsw,
    const float* __restrict__ bd,
    float* __restrict__ out)
{
    __shared__ __align__(16) ushort_t lA[2 * 8 * 64 * 8];
    __shared__ __align__(16) ushort_t lB[2 * 8 * 64 * 8];
    const int tid = threadIdx.x, w = tid >> 6, lane = tid & 63;
    const int id = blockIdx.x;
    const int rt = ((id >> 5) << 3) | (id & 7);
    const int ct = (id >> 3) & 3;
    const int r0 = rt << 7, f0 = ct << 7;
    const int wr = w >> 1, wc = w & 1;

    f32x4 acc[4][4];
    #pragma unroll
    for (int m = 0; m < 4; ++m)
        #pragma unroll
        for (int n = 0; n < 4; ++n) acc[m][n] = (f32x4){0.f, 0.f, 0.f, 0.f};

    for (int kc = 0; kc < Hh; kc += 64) {
        #pragma unroll
        for (int i = 0; i < 4; ++i) {
            int p = (i << 8) + tid;
            int row = p >> 3, kpp = p & 7;
            bf16x8 v = *(const bf16x8*)(seq + (size_t)(r0 + row) * Hh + kc + (kpp << 3));
            int kk = kpp >> 2, q = kpp & 3, msub = row >> 4, mm = row & 15;
            int pos = (q << 4) | (mm ^ (((kk << 2) + q) & 15));
            *(bf16x8*)&lA[((((kk << 3) + msub) << 6) + pos) << 3] = v;
        }
        #pragma unroll
        for (int i = 0; i < 4; ++i) {
            int d = (i << 8) + tid;
            int kk = d >> 9, csub = (d >> 6) & 7, ln = d & 63;
            int nt = (ct << 3) + csub;
            bf16x8 v = *(const bf16x8*)(Wsw + (((size_t)(nt * 32 + (kc >> 5) + kk)) << 9) + (ln << 3));
            *(bf16x8*)&lB[d << 3] = v;
        }
        __syncthreads();
        const int qq = lane >> 4, mm = lane & 15;
        #pragma unroll
        for (int kk = 0; kk < 2; ++kk) {
            const int pos = (qq << 4) | (mm ^ (((kk << 2) + qq) & 15));
            bf16x8 af[4], bfr[4];
            #pragma unroll
            for (int m = 0; m < 4; ++m)
                af[m] = *(const bf16x8*)&lA[((((kk << 3) + (wr << 2) + m) << 6) + pos) << 3];
            #pragma unroll
            for (int n = 0; n < 4; ++n)
                bfr[n] = *(const bf16x8*)&lB[((((kk << 3) + (wc << 2) + n) << 6) + lane) << 3];
            #pragma unroll
            for (int m = 0; m < 4; ++m)
                #pragma unroll
                for (int n = 0; n < 4; ++n)
                    acc[m][n] = __builtin_amdgcn_mfma_f32_16x16x32_bf16(
                        af[m], bfr[n], acc[m][n], 0, 0, 0);
        }
        __syncthreads();
    }

    int q = lane >> 4, nl = lane & 15;
    float bdv[4];
    #pragma unroll
    for (int n = 0; n < 4; ++n) bdv[n] = bd[f0 + (wc << 6) + (n << 4) + nl];
    #pragma unroll
    for (int m = 0; m < 4; ++m)
        #pragma unroll
        for (int r = 0; r < 4; ++r) {
            int grow2 = r0 + (wr << 6) + (m << 4) + (q << 2) + r;  // = t*256 + b
            int tt = grow2 >> 8, bb = grow2 & 255;
            float* op = out + ((size_t)((bb << 7) + tt) << 9);
            #pragma unroll
            for (int n = 0; n < 4; ++n)
                op[f0 + (wc << 6) + (n << 4) + nl] = acc[m][n][r] + bdv[n];
        }
}

// ---------- launch ----------
extern "C" void kernel_launch(void* const* d_in, const int* in_sizes, int n_in,
                              void* d_out, int out_size, void* d_ws, size_t ws_size,
                              hipStream_t stream)
{
    const float* x0 = (const float*)d_in[0];
    const float* h0 = (const float*)d_in[1];
    const float* c0 = (const float*)d_in[2];
    const float* W  = (const float*)d_in[3];
    const float* U  = (const float*)d_in[4];
    const float* b  = (const float*)d_in[5];
    const float* Wd = (const float*)d_in[6];
    const float* bd = (const float*)d_in[7];
    float* out = (float*)d_out;

    const size_t OFF_MCAT = 0;                  // 16,777,216
    const size_t OFF_MSUM = 16777216;           //  8,388,608
    const size_t OFF_WSW  = 25165824;           //  1,048,576
    const size_t OFF_A0   = 26214400;           //  1,048,576
    const size_t OFF_SEQ  = 27262976;           // 67,108,864
    const size_t OFF_BAR  = 94371840;           //      4,096
    const size_t WS_NEED  = 94375936;
    if (ws_size < WS_NEED) return;

    char* ws = (char*)d_ws;
    ushort_t* Mcat = (ushort_t*)(ws + OFF_MCAT);
    ushort_t* Msum = (ushort_t*)(ws + OFF_MSUM);
    ushort_t* Wsw  = (ushort_t*)(ws + OFF_WSW);
    ushort_t* A0   = (ushort_t*)(ws + OFF_A0);
    ushort_t* seq  = (ushort_t*)(ws + OFF_SEQ);
    int*      bar  = (int*)(ws + OFF_BAR);
    float* cws = out;   // c-state scratch: dead before emit overwrites out

    zero_bar<<<4, 256, 0, stream>>>(bar);
    mk_a0<<<2048, 256, 0, stream>>>(x0, h0, A0);
    swz<<<4096, 256, 0, stream>>>(W, U, Mcat, 2048, 4096, 1, 2048 * 4096);
    swz<<<2048, 256, 0, stream>>>(W, U, Msum, 1024, 4096, 0, 1024 * 4096);
    swz<<<512, 256, 0, stream>>>(Wd, nullptr, Wsw, 1024, 512, 2, 1024 * 512);

    lstm_step<<<256, 256, 0, stream>>>(A0, 2048, Mcat, c0, cws, seq, b);
    lstm_scan<<<256, 256, 0, stream>>>(seq, Msum, b, cws, bar);

    emit<<<1024, 256, 0, stream>>>(seq, Wsw, bd, out);
}

// Round 8
// 730.056 us; speedup vs baseline: 1.5995x; 1.1345x over previous
//
#include <hip/hip_runtime.h>
#include <cstddef>
#include <cstdint>

typedef unsigned short ushort_t;
typedef __attribute__((ext_vector_type(8))) short bf16x8;
typedef __attribute__((ext_vector_type(4))) float f32x4;

#define Bb 256
#define Hh 1024
#define Ff 512
#define Tt 128

// ---------- helpers ----------
__device__ __forceinline__ ushort_t f2bf(float f) {
    unsigned int u = __float_as_uint(f);
    unsigned int r = (u + 0x7FFFu + ((u >> 16) & 1u)) >> 16;
    return (ushort_t)r;
}
__device__ __forceinline__ float sigf(float x)  { return 1.0f / (1.0f + __expf(-x)); }
__device__ __forceinline__ float tanhf_(float x){ return 2.0f / (1.0f + __expf(-2.0f * x)) - 1.0f; }

// LDS-only barrier: drains lgkmcnt (my ds reads+writes done) but leaves global
// loads IN FLIGHT across the barrier (__syncthreads would force vmcnt(0) and
// serialize the A-prefetch pipeline — the m97-structure stall). Memory-clobber
// asm on both sides fences compiler reordering of LDS ops across the barrier.
__device__ __forceinline__ void lds_barrier() {
    asm volatile("s_waitcnt lgkmcnt(0)" ::: "memory");
    __builtin_amdgcn_s_barrier();
    asm volatile("" ::: "memory");
}

// ---------- weight swizzle: row-major fp32 [K][N] -> bf16 B-fragment blocks ----------
// 1KB blocks [ntile][kstep]; within: lane=(koff/8)*16+(n%16), j=koff%8.
// modes 0/1: gate-interleaved ntile = ugroup*4 + gate. mode 2 (Wd): plain.
__global__ void swz(const float* __restrict__ s0, const float* __restrict__ s1,
                    ushort_t* __restrict__ dst, int K, int N, int mode, int total)
{
    int KB = K >> 5;
    for (int idx = blockIdx.x * blockDim.x + threadIdx.x; idx < total;
         idx += gridDim.x * blockDim.x) {
        int blk   = idx >> 9;
        int lane  = (idx >> 3) & 63;
        int j     = idx & 7;
        int ntile = blk / KB;
        int kstep = blk - ntile * KB;
        int k = (kstep << 5) + ((lane >> 4) << 3) + j;
        int n;
        if (mode == 2) n = (ntile << 4) + (lane & 15);
        else           n = ((ntile & 3) << 10) + ((ntile >> 2) << 4) + (lane & 15);
        float v;
        if (mode == 0)      v = s0[(size_t)k * N + n] + s1[(size_t)k * N + n];
        else if (mode == 1) v = (k < 1024) ? s0[(size_t)k * N + n]
                                           : s1[(size_t)(k - 1024) * N + n];
        else                v = s0[(size_t)k * N + n];
        dst[idx] = f2bf(v);
    }
}

// ---------- A0 = [x0 | h0] as bf16, row-major [256][2048] ----------
__global__ void mk_a0(const float* __restrict__ x0, const float* __restrict__ h0,
                      ushort_t* __restrict__ a0)
{
    int idx = blockIdx.x * blockDim.x + threadIdx.x;
    if (idx >= Bb * 2048) return;
    int r = idx >> 11, k = idx & 2047;
    float v = (k < 1024) ? x0[r * 1024 + k] : h0[r * 1024 + k - 1024];
    a0[idx] = f2bf(v);
}

__global__ void zero_bar(int* bar) {
    int i = blockIdx.x * blockDim.x + threadIdx.x;
    if (i < 1024) bar[i] = 0;
}

// bar layout (ints, 128B-spaced lines):
//   bar[g*32] : arrival counter for logical group g = blockIdx&7 (32 blocks).
//   All ops agent-scope RMW -> execute at the coherent point (LLC): converges
//   for ANY block->XCD placement (proven r4).

// ---------- step 0 (K=2048, Mcat streamed): round-2 kernel, proven ----------
__global__ __launch_bounds__(256) void lstm_step(
    const ushort_t* __restrict__ Ap, int K,
    const ushort_t* __restrict__ Bw,
    const float* cin, float* cout,
    ushort_t* __restrict__ seqt,
    const float* __restrict__ bias)
{
    __shared__ __align__(16) ushort_t lA[32 * 512];
    __shared__ __align__(16) ushort_t lB[32 * 512];

    const int tid = threadIdx.x, w = tid >> 6, lane = tid & 63;
    const int id = blockIdx.x;
    const int ntg = ((id & 7) << 3) | (id >> 5);
    const int bt  = (id >> 3) & 3;
    const int r0 = bt << 6, hb = ntg << 4;
    const int wr = w >> 1, wc = w & 1;
    const int KB = K >> 5;

    f32x4 acc[2][2];
    #pragma unroll
    for (int m = 0; m < 2; ++m)
        #pragma unroll
        for (int n = 0; n < 2; ++n) acc[m][n] = (f32x4){0.f, 0.f, 0.f, 0.f};

    const int kp = tid & 31;
    const int q_a = kp & 3, kk_a = kp >> 2;

    for (int kc = 0; kc < K; kc += 256) {
        bf16x8 va[8];
        #pragma unroll
        for (int i = 0; i < 8; ++i) {
            int row = (i << 3) + (tid >> 5);
            va[i] = *(const bf16x8*)(Ap + (size_t)(r0 + row) * K + kc + (kp << 3));
        }
        bf16x8 vb[8];
        #pragma unroll
        for (int i = 0; i < 8; ++i)
            vb[i] = *(const bf16x8*)(Bw +
                ((((size_t)((ntg << 2) + w)) * KB + (kc >> 5) + i) << 9) + (lane << 3));
        #pragma unroll
        for (int i = 0; i < 8; ++i) {
            int row = (i << 3) + (tid >> 5);
            int msub = row >> 4, mm = row & 15;
            int pos = (q_a << 4) | (mm ^ (((kk_a << 2) + q_a) & 15));
            *(bf16x8*)&lA[((((kk_a << 2) + msub) << 6) + pos) << 3] = va[i];
        }
        #pragma unroll
        for (int i = 0; i < 8; ++i)
            *(bf16x8*)&lB[(((i << 2) + w) << 9) + (lane << 3)] = vb[i];
        __syncthreads();

        #pragma unroll
        for (int kk = 0; kk < 8; ++kk) {
            const int qq = lane >> 4, mm = lane & 15;
            const int pos = (qq << 4) | (mm ^ (((kk << 2) + qq) & 15));
            bf16x8 af[2], bfr[2];
            #pragma unroll
            for (int m = 0; m < 2; ++m)
                af[m] = *(const bf16x8*)&lA[((((kk << 2) + (wr << 1) + m) << 6) + pos) << 3];
            #pragma unroll
            for (int n = 0; n < 2; ++n)
                bfr[n] = *(const bf16x8*)&lB[((((kk << 2) + (wc << 1) + n) << 6) + lane) << 3];
            #pragma unroll
            for (int m = 0; m < 2; ++m)
                #pragma unroll
                for (int n = 0; n < 2; ++n)
                    acc[m][n] = __builtin_amdgcn_mfma_f32_16x16x32_bf16(
                        af[m], bfr[n], acc[m][n], 0, 0, 0);
        }
        __syncthreads();
    }

    float* lZ = (float*)lA;
    {
        int q = lane >> 4, nl = lane & 15;
        #pragma unroll
        for (int m = 0; m < 2; ++m)
            #pragma unroll
            for (int n = 0; n < 2; ++n)
                #pragma unroll
                for (int r = 0; r < 4; ++r)
                    lZ[((wr << 5) + (m << 4) + (q << 2) + r) * 68 +
                       (wc << 5) + (n << 4) + nl] = acc[m][n][r];
    }
    __syncthreads();

    #pragma unroll
    for (int i = 0; i < 4; ++i) {
        int idx = (i << 8) + tid;
        int row = idx >> 4, u = idx & 15;
        float zi = lZ[row * 68 +      u] + bias[       hb + u];
        float zf = lZ[row * 68 + 16 + u] + bias[1024 + hb + u];
        float zg = lZ[row * 68 + 32 + u] + bias[2048 + hb + u];
        float zo = lZ[row * 68 + 48 + u] + bias[3072 + hb + u];
        size_t cidx = (size_t)(r0 + row) * Hh + hb + u;
        float cp = cin[cidx];
        float cn = sigf(zf) * cp + sigf(zi) * tanhf_(zg);
        cout[cidx] = cn;
        seqt[cidx] = f2bf(sigf(zo) * tanhf_(cn));
    }
}

// ---------- persistent scan, steps 1..127 — full-step prefetch + lgkm-only barriers ----------
// Group g = id&7 owns rows [32g,32g+32); block s = id>>3 owns h-cols [32s,32s+32)
// (Z tile 32x128). r7 structure + B pinned in AGPRs (r7: small win, kept).
// CHANGE vs r7 (one mechanism): all 16 A-loads issued at step start and the
// compute-phase __syncthreads replaced by lds_barrier() (lgkmcnt-only). r7's
// per-kc __syncthreads forced vmcnt(0) before every s_barrier -> in-loop
// prefetch loads could never stay in flight: ~8 x ~500cy forced LLC-latency
// stalls per step (the documented m97 barrier-drain stall). Now the loads
// drain progressively via compiler-counted vmcnt waits at each stage-write.
// Publish drain + post-poll sync remain full __syncthreads (vmcnt must drain
// there). Group barrier/publish primitives unchanged (proven r4).
__global__ __launch_bounds__(256, 1) void lstm_scan(
    ushort_t* __restrict__ seq,
    const ushort_t* __restrict__ Msum,
    const float* __restrict__ bias,
    const float* __restrict__ cin,
    int* __restrict__ bar)
{
    __shared__ __align__(16) ushort_t lA[2][4096];   // 2 x 8KB A chunks (32 rows x 128 k)

    const int tid = threadIdx.x, w = tid >> 6, lane = tid & 63;
    const int id = blockIdx.x;
    const int g  = id & 7;           // batch-row group (self-contained scan)
    const int s  = id >> 3;          // 0..31: h-col tile within group
    const int r0 = g << 5;           // 32 batch rows
    const int hb = s << 5;           // 32 h cols
    int* const barw = &bar[g << 5];  // group arrival counter (one line per group)

    // ---- resident B: wave w holds ntl = 2w, 2w+1; PINNED IN AGPRs (r7) ----
    bf16x8 Brg[2][32];
    #pragma unroll
    for (int n = 0; n < 2; ++n) {
        const int ntl = (w << 1) + n;
        const int gnt = (((s << 1) + (ntl >> 2)) << 2) + (ntl & 3);
        const ushort_t* bp = Msum + (((size_t)gnt << 5) << 9) + (lane << 3);
        #pragma unroll
        for (int ks = 0; ks < 32; ++ks) {
            Brg[n][ks] = *(const bf16x8*)(bp + ((size_t)ks << 9));
            asm volatile("" : "+a"(Brg[n][ks]));
        }
    }

    // ---- c-state + bias in registers: thread owns row=tid>>3, cols gu4..gu4+3 ----
    const int grow = tid >> 3, gu4 = (tid & 7) << 2;
    float c_reg[4], bi[4], bfv[4], bgv[4], bo[4];
    #pragma unroll
    for (int j = 0; j < 4; ++j) {
        int u = gu4 + j;
        c_reg[j] = cin[(size_t)(r0 + grow) * Hh + hb + u];
        bi[j]  = bias[       hb + u];
        bfv[j] = bias[1024 + hb + u];
        bgv[j] = bias[2048 + hb + u];
        bo[j]  = bias[3072 + hb + u];
    }

    float* lZ = (float*)lA;   // 32 x 128 f32 overlay (16KB)

    // A staging geometry: piece p = i*256+tid (i=0,1): row = i*16 + (tid>>4), kp = tid&15
    const int kp  = tid & 15;
    const int q_a = kp & 3, kk_a = kp >> 2;
    const int mm_s  = tid >> 4;
    const int pos_s = (q_a << 4) | (mm_s ^ (((kk_a << 2) + q_a) & 15));
    const int lw0   = (((kk_a << 1) << 6) | pos_s) << 3;      // ushort idx; piece i adds 512
    const size_t ga0 = (size_t)(r0 + mm_s) * Hh + (kp << 3);  // global base; piece i adds 1<<14

    #pragma unroll 1
    for (int t = 1; t < Tt; ++t) {
        const ushort_t* Ap = seq + ((size_t)(t - 1) << 18) + ga0;

        f32x4 acc[2][2];
        #pragma unroll
        for (int m = 0; m < 2; ++m)
            #pragma unroll
            for (int n = 0; n < 2; ++n) acc[m][n] = (f32x4){0.f, 0.f, 0.f, 0.f};

        // ---- full-step prefetch: issue ALL 16 A-loads now; they stay in
        // flight across the lgkm-only barriers below ----
        bf16x8 rA[8][2];
        #pragma unroll
        for (int c = 0; c < 8; ++c)
            #pragma unroll
            for (int i = 0; i < 2; ++i)
                rA[c][i] = *(const bf16x8*)(Ap + (i << 14) + (c << 7));

        // stage chunk 0 (compiler emits counted vmcnt wait for its 2 loads)
        #pragma unroll
        for (int i = 0; i < 2; ++i)
            *(bf16x8*)&lA[0][lw0 + (i << 9)] = rA[0][i];
        lds_barrier();

        #pragma unroll   // full unroll: Brg/rA indices must be static
        for (int kc = 0; kc < 8; ++kc) {
            if (kc < 7) {   // stage chunk kc+1 into the other buffer
                #pragma unroll
                for (int i = 0; i < 2; ++i)
                    *(bf16x8*)&lA[(kc + 1) & 1][lw0 + (i << 9)] = rA[kc + 1][i];
            }
            const ushort_t* lAc = lA[kc & 1];
            const int qq = lane >> 4, mr = lane & 15;
            #pragma unroll
            for (int kk = 0; kk < 4; ++kk) {
                const int pos = (qq << 4) | (mr ^ (((kk << 2) + qq) & 15));
                const int ks = (kc << 2) + kk;
                bf16x8 af0 = *(const bf16x8*)&lAc[((((kk << 1) + 0) << 6) | pos) << 3];
                bf16x8 af1 = *(const bf16x8*)&lAc[((((kk << 1) + 1) << 6) | pos) << 3];
                acc[0][0] = __builtin_amdgcn_mfma_f32_16x16x32_bf16(af0, Brg[0][ks], acc[0][0], 0, 0, 0);
                acc[0][1] = __builtin_amdgcn_mfma_f32_16x16x32_bf16(af0, Brg[1][ks], acc[0][1], 0, 0, 0);
                acc[1][0] = __builtin_amdgcn_mfma_f32_16x16x32_bf16(af1, Brg[0][ks], acc[1][0], 0, 0, 0);
                acc[1][1] = __builtin_amdgcn_mfma_f32_16x16x32_bf16(af1, Brg[1][ks], acc[1][1], 0, 0, 0);
            }
            lds_barrier();   // lgkm-only: prefetch loads remain in flight
        }

        // Z exchange into lZ (overlays lA), skew col+(5*row) -> <=2-way conflicts
        {
            const int q = lane >> 4, nl = lane & 15;
            #pragma unroll
            for (int m = 0; m < 2; ++m)
                #pragma unroll
                for (int n = 0; n < 2; ++n)
                    #pragma unroll
                    for (int r = 0; r < 4; ++r) {
                        int row = (m << 4) + (q << 2) + r;
                        int col = (((w << 1) + n) << 4) + nl;
                        lZ[(row << 7) + ((col + row * 5) & 127)] = acc[m][n][r];
                    }
        }
        lds_barrier();

        // gates + c/h update; h published via ONE relaxed agent-scope 8B atomic
        // exchange per thread (RMW lands at LLC -> visible to any consumer XCD)
        {
            const int rb5 = grow * 5;
            unsigned long long pk = 0;
            #pragma unroll
            for (int j = 0; j < 4; ++j) {
                int u = gu4 + j;
                int cb = ((u >> 4) << 6) + (u & 15);   // gate-0 Z col for this h col
                float zi = lZ[(grow << 7) + ((cb      + rb5) & 127)] + bi[j];
                float zf = lZ[(grow << 7) + ((cb + 16 + rb5) & 127)] + bfv[j];
                float zg = lZ[(grow << 7) + ((cb + 32 + rb5) & 127)] + bgv[j];
                float zo = lZ[(grow << 7) + ((cb + 48 + rb5) & 127)] + bo[j];
                float cn = sigf(zf) * c_reg[j] + sigf(zi) * tanhf_(zg);
                c_reg[j] = cn;
                pk |= (unsigned long long)f2bf(sigf(zo) * tanhf_(cn)) << (j << 4);
            }
            __hip_atomic_exchange(
                (unsigned long long*)&seq[((size_t)t << 18) +
                                          (size_t)(r0 + grow) * Hh + hb + gu4],
                pk, __ATOMIC_RELAXED, __HIP_MEMORY_SCOPE_AGENT);
        }

        if (t < Tt - 1) {
            __syncthreads();   // FULL drain: exchanges acked at the coherent point
            if (tid == 0) {
                // per-group barrier: agent-scope RMW arrival + RMW poll on one
                // LLC line (32 writers); no cross-group coupling
                __hip_atomic_fetch_add(barw, 1, __ATOMIC_RELAXED,
                                       __HIP_MEMORY_SCOPE_AGENT);
                int guard = 0;
                while (__hip_atomic_fetch_add(barw, 0, __ATOMIC_RELAXED,
                                              __HIP_MEMORY_SCOPE_AGENT) < (t << 5)
                       && ++guard < 30000)
                    __builtin_amdgcn_s_sleep(2);
            }
            __syncthreads();
        }
    }
}

// ---------- batched emission, XCD-pinned, XOR-swizzled A staging ----------
__global__ __launch_bounds__(256) void emit(
    const ushort_t* __restrict__ seq,
    const ushort_t* __restrict__ Wsw,
    const float* __restrict__ bd,
    float* __restrict__ out)
{
    __shared__ __align__(16) ushort_t lA[2 * 8 * 64 * 8];
    __shared__ __align__(16) ushort_t lB[2 * 8 * 64 * 8];
    const int tid = threadIdx.x, w = tid >> 6, lane = tid & 63;
    const int id = blockIdx.x;
    const int rt = ((id >> 5) << 3) | (id & 7);
    const int ct = (id >> 3) & 3;
    const int r0 = rt << 7, f0 = ct << 7;
    const int wr = w >> 1, wc = w & 1;

    f32x4 acc[4][4];
    #pragma unroll
    for (int m = 0; m < 4; ++m)
        #pragma unroll
        for (int n = 0; n < 4; ++n) acc[m][n] = (f32x4){0.f, 0.f, 0.f, 0.f};

    for (int kc = 0; kc < Hh; kc += 64) {
        #pragma unroll
        for (int i = 0; i < 4; ++i) {
            int p = (i << 8) + tid;
            int row = p >> 3, kpp = p & 7;
            bf16x8 v = *(const bf16x8*)(seq + (size_t)(r0 + row) * Hh + kc + (kpp << 3));
            int kk = kpp >> 2, q = kpp & 3, msub = row >> 4, mm = row & 15;
            int pos = (q << 4) | (mm ^ (((kk << 2) + q) & 15));
            *(bf16x8*)&lA[((((kk << 3) + msub) << 6) + pos) << 3] = v;
        }
        #pragma unroll
        for (int i = 0; i < 4; ++i) {
            int d = (i << 8) + tid;
            int kk = d >> 9, csub = (d >> 6) & 7, ln = d & 63;
            int nt = (ct << 3) + csub;
            bf16x8 v = *(const bf16x8*)(Wsw + (((size_t)(nt * 32 + (kc >> 5) + kk)) << 9) + (ln << 3));
            *(bf16x8*)&lB[d << 3] = v;
        }
        __syncthreads();
        const int qq = lane >> 4, mm = lane & 15;
        #pragma unroll
        for (int kk = 0; kk < 2; ++kk) {
            const int pos = (qq << 4) | (mm ^ (((kk << 2) + qq) & 15));
            bf16x8 af[4], bfr[4];
            #pragma unroll
            for (int m = 0; m < 4; ++m)
                af[m] = *(const bf16x8*)&lA[((((kk << 3) + (wr << 2) + m) << 6) + pos) << 3];
            #pragma unroll
            for (int n = 0; n < 4; ++n)
                bfr[n] = *(const bf16x8*)&lB[((((kk << 3) + (wc << 2) + n) << 6) + lane) << 3];
            #pragma unroll
            for (int m = 0; m < 4; ++m)
                #pragma unroll
                for (int n = 0; n < 4; ++n)
                    acc[m][n] = __builtin_amdgcn_mfma_f32_16x16x32_bf16(
                        af[m], bfr[n], acc[m][n], 0, 0, 0);
        }
        __syncthreads();
    }

    int q = lane >> 4, nl = lane & 15;
    float bdv[4];
    #pragma unroll
    for (int n = 0; n < 4; ++n) bdv[n] = bd[f0 + (wc << 6) + (n << 4) + nl];
    #pragma unroll
    for (int m = 0; m < 4; ++m)
        #pragma unroll
        for (int r = 0; r < 4; ++r) {
            int grow2 = r0 + (wr << 6) + (m << 4) + (q << 2) + r;  // = t*256 + b
            int tt = grow2 >> 8, bb = grow2 & 255;
            float* op = out + ((size_t)((bb << 7) + tt) << 9);
            #pragma unroll
            for (int n = 0; n < 4; ++n)
                op[f0 + (wc << 6) + (n << 4) + nl] = acc[m][n][r] + bdv[n];
        }
}

// ---------- launch ----------
extern "C" void kernel_launch(void* const* d_in, const int* in_sizes, int n_in,
                              void* d_out, int out_size, void* d_ws, size_t ws_size,
                              hipStream_t stream)
{
    const float* x0 = (const float*)d_in[0];
    const float* h0 = (const float*)d_in[1];
    const float* c0 = (const float*)d_in[2];
    const float* W  = (const float*)d_in[3];
    const float* U  = (const float*)d_in[4];
    const float* b  = (const float*)d_in[5];
    const float* Wd = (const float*)d_in[6];
    const float* bd = (const float*)d_in[7];
    float* out = (float*)d_out;

    const size_t OFF_MCAT = 0;                  // 16,777,216
    const size_t OFF_MSUM = 16777216;           //  8,388,608
    const size_t OFF_WSW  = 25165824;           //  1,048,576
    const size_t OFF_A0   = 26214400;           //  1,048,576
    const size_t OFF_SEQ  = 27262976;           // 67,108,864
    const size_t OFF_BAR  = 94371840;           //      4,096
    const size_t WS_NEED  = 94375936;
    if (ws_size < WS_NEED) return;

    char* ws = (char*)d_ws;
    ushort_t* Mcat = (ushort_t*)(ws + OFF_MCAT);
    ushort_t* Msum = (ushort_t*)(ws + OFF_MSUM);
    ushort_t* Wsw  = (ushort_t*)(ws + OFF_WSW);
    ushort_t* A0   = (ushort_t*)(ws + OFF_A0);
    ushort_t* seq  = (ushort_t*)(ws + OFF_SEQ);
    int*      bar  = (int*)(ws + OFF_BAR);
    float* cws = out;   // c-state scratch: dead before emit overwrites out

    zero_bar<<<4, 256, 0, stream>>>(bar);
    mk_a0<<<2048, 256, 0, stream>>>(x0, h0, A0);
    swz<<<4096, 256, 0, stream>>>(W, U, Mcat, 2048, 4096, 1, 2048 * 4096);
    swz<<<2048, 256, 0, stream>>>(W, U, Msum, 1024, 4096, 0, 1024 * 4096);
    swz<<<512, 256, 0, stream>>>(Wd, nullptr, Wsw, 1024, 512, 2, 1024 * 512);

    lstm_step<<<256, 256, 0, stream>>>(A0, 2048, Mcat, c0, cws, seq, b);
    lstm_scan<<<256, 256, 0, stream>>>(seq, Msum, b, cws, bar);

    emit<<<1024, 256, 0, stream>>>(seq, Wsw, bd, out);
}

// Round 9
// 727.230 us; speedup vs baseline: 1.6057x; 1.0039x over previous
//
#include <hip/hip_runtime.h>
#include <cstddef>
#include <cstdint>

typedef unsigned short ushort_t;
typedef __attribute__((ext_vector_type(8))) short bf16x8;
typedef __attribute__((ext_vector_type(4))) float f32x4;

#define Bb 256
#define Hh 1024
#define Ff 512
#define Tt 128

// ---------- helpers ----------
__device__ __forceinline__ ushort_t f2bf(float f) {
    unsigned int u = __float_as_uint(f);
    unsigned int r = (u + 0x7FFFu + ((u >> 16) & 1u)) >> 16;
    return (ushort_t)r;
}
__device__ __forceinline__ float sigf(float x)  { return 1.0f / (1.0f + __expf(-x)); }
__device__ __forceinline__ float tanhf_(float x){ return 2.0f / (1.0f + __expf(-2.0f * x)) - 1.0f; }

// LDS-only barrier: drains lgkmcnt (my ds reads+writes done) but leaves global
// loads IN FLIGHT across the barrier (__syncthreads would force vmcnt(0) and
// serialize the A-prefetch pipeline — the m97-structure stall). Memory-clobber
// asm on both sides fences compiler reordering of LDS ops across the barrier.
__device__ __forceinline__ void lds_barrier() {
    asm volatile("s_waitcnt lgkmcnt(0)" ::: "memory");
    __builtin_amdgcn_s_barrier();
    asm volatile("" ::: "memory");
}

// ---------- weight swizzle: row-major fp32 [K][N] -> bf16 B-fragment blocks ----------
// 1KB blocks [ntile][kstep]; within: lane=(koff/8)*16+(n%16), j=koff%8.
// modes 0/1: gate-interleaved ntile = ugroup*4 + gate. mode 2 (Wd): plain.
__global__ void swz(const float* __restrict__ s0, const float* __restrict__ s1,
                    ushort_t* __restrict__ dst, int K, int N, int mode, int total)
{
    int KB = K >> 5;
    for (int idx = blockIdx.x * blockDim.x + threadIdx.x; idx < total;
         idx += gridDim.x * blockDim.x) {
        int blk   = idx >> 9;
        int lane  = (idx >> 3) & 63;
        int j     = idx & 7;
        int ntile = blk / KB;
        int kstep = blk - ntile * KB;
        int k = (kstep << 5) + ((lane >> 4) << 3) + j;
        int n;
        if (mode == 2) n = (ntile << 4) + (lane & 15);
        else           n = ((ntile & 3) << 10) + ((ntile >> 2) << 4) + (lane & 15);
        float v;
        if (mode == 0)      v = s0[(size_t)k * N + n] + s1[(size_t)k * N + n];
        else if (mode == 1) v = (k < 1024) ? s0[(size_t)k * N + n]
                                           : s1[(size_t)(k - 1024) * N + n];
        else                v = s0[(size_t)k * N + n];
        dst[idx] = f2bf(v);
    }
}

// ---------- A0 = [x0 | h0] as bf16, row-major [256][2048] ----------
__global__ void mk_a0(const float* __restrict__ x0, const float* __restrict__ h0,
                      ushort_t* __restrict__ a0)
{
    int idx = blockIdx.x * blockDim.x + threadIdx.x;
    if (idx >= Bb * 2048) return;
    int r = idx >> 11, k = idx & 2047;
    float v = (k < 1024) ? x0[r * 1024 + k] : h0[r * 1024 + k - 1024];
    a0[idx] = f2bf(v);
}

__global__ void zero_bar(int* bar) {
    int i = blockIdx.x * blockDim.x + threadIdx.x;
    if (i < 1024) bar[i] = 0;
}

// bar layout (ints, 128B-spaced lines):
//   bar[g*32] : arrival counter for logical group g = blockIdx&7 (32 blocks).
//   All ops agent-scope RMW -> execute at the coherent point (LLC): converges
//   for ANY block->XCD placement (proven r4).

// ---------- step 0 (K=2048, Mcat streamed): round-2 kernel, proven ----------
__global__ __launch_bounds__(256) void lstm_step(
    const ushort_t* __restrict__ Ap, int K,
    const ushort_t* __restrict__ Bw,
    const float* cin, float* cout,
    ushort_t* __restrict__ seqt,
    const float* __restrict__ bias)
{
    __shared__ __align__(16) ushort_t lA[32 * 512];
    __shared__ __align__(16) ushort_t lB[32 * 512];

    const int tid = threadIdx.x, w = tid >> 6, lane = tid & 63;
    const int id = blockIdx.x;
    const int ntg = ((id & 7) << 3) | (id >> 5);
    const int bt  = (id >> 3) & 3;
    const int r0 = bt << 6, hb = ntg << 4;
    const int wr = w >> 1, wc = w & 1;
    const int KB = K >> 5;

    f32x4 acc[2][2];
    #pragma unroll
    for (int m = 0; m < 2; ++m)
        #pragma unroll
        for (int n = 0; n < 2; ++n) acc[m][n] = (f32x4){0.f, 0.f, 0.f, 0.f};

    const int kp = tid & 31;
    const int q_a = kp & 3, kk_a = kp >> 2;

    for (int kc = 0; kc < K; kc += 256) {
        bf16x8 va[8];
        #pragma unroll
        for (int i = 0; i < 8; ++i) {
            int row = (i << 3) + (tid >> 5);
            va[i] = *(const bf16x8*)(Ap + (size_t)(r0 + row) * K + kc + (kp << 3));
        }
        bf16x8 vb[8];
        #pragma unroll
        for (int i = 0; i < 8; ++i)
            vb[i] = *(const bf16x8*)(Bw +
                ((((size_t)((ntg << 2) + w)) * KB + (kc >> 5) + i) << 9) + (lane << 3));
        #pragma unroll
        for (int i = 0; i < 8; ++i) {
            int row = (i << 3) + (tid >> 5);
            int msub = row >> 4, mm = row & 15;
            int pos = (q_a << 4) | (mm ^ (((kk_a << 2) + q_a) & 15));
            *(bf16x8*)&lA[((((kk_a << 2) + msub) << 6) + pos) << 3] = va[i];
        }
        #pragma unroll
        for (int i = 0; i < 8; ++i)
            *(bf16x8*)&lB[(((i << 2) + w) << 9) + (lane << 3)] = vb[i];
        __syncthreads();

        #pragma unroll
        for (int kk = 0; kk < 8; ++kk) {
            const int qq = lane >> 4, mm = lane & 15;
            const int pos = (qq << 4) | (mm ^ (((kk << 2) + qq) & 15));
            bf16x8 af[2], bfr[2];
            #pragma unroll
            for (int m = 0; m < 2; ++m)
                af[m] = *(const bf16x8*)&lA[((((kk << 2) + (wr << 1) + m) << 6) + pos) << 3];
            #pragma unroll
            for (int n = 0; n < 2; ++n)
                bfr[n] = *(const bf16x8*)&lB[((((kk << 2) + (wc << 1) + n) << 6) + lane) << 3];
            #pragma unroll
            for (int m = 0; m < 2; ++m)
                #pragma unroll
                for (int n = 0; n < 2; ++n)
                    acc[m][n] = __builtin_amdgcn_mfma_f32_16x16x32_bf16(
                        af[m], bfr[n], acc[m][n], 0, 0, 0);
        }
        __syncthreads();
    }

    float* lZ = (float*)lA;
    {
        int q = lane >> 4, nl = lane & 15;
        #pragma unroll
        for (int m = 0; m < 2; ++m)
            #pragma unroll
            for (int n = 0; n < 2; ++n)
                #pragma unroll
                for (int r = 0; r < 4; ++r)
                    lZ[((wr << 5) + (m << 4) + (q << 2) + r) * 68 +
                       (wc << 5) + (n << 4) + nl] = acc[m][n][r];
    }
    __syncthreads();

    #pragma unroll
    for (int i = 0; i < 4; ++i) {
        int idx = (i << 8) + tid;
        int row = idx >> 4, u = idx & 15;
        float zi = lZ[row * 68 +      u] + bias[       hb + u];
        float zf = lZ[row * 68 + 16 + u] + bias[1024 + hb + u];
        float zg = lZ[row * 68 + 32 + u] + bias[2048 + hb + u];
        float zo = lZ[row * 68 + 48 + u] + bias[3072 + hb + u];
        size_t cidx = (size_t)(r0 + row) * Hh + hb + u;
        float cp = cin[cidx];
        float cn = sigf(zf) * cp + sigf(zi) * tanhf_(zg);
        cout[cidx] = cn;
        seqt[cidx] = f2bf(sigf(zo) * tanhf_(cn));
    }
}

// ---------- persistent scan, steps 1..127 — FULL-TILE LDS staging, barrier-free MFMA ----------
// Group g = id&7 owns rows [32g,32g+32); block s = id>>3 owns h-cols [32s,32s+32)
// (Z tile 32x128). r8 structure (full-step prefetch + lgkm-only barriers +
// AGPR-pinned B + proven r4 publish/group-barrier).
// CHANGE vs r8 (one mechanism): the A tile (32x1024 bf16 = 64KB) is staged
// WHOLE into LDS — the 2x8KB double-buffer and its 8 per-kc lds_barriers were
// a streaming-GEMM inheritance with no capacity justification (LDS=160KB).
// Now: 16 loads (already issued up front since r8) -> 16 writes draining on
// counted vmcnt -> ONE lds_barrier -> 128 MFMAs + 64 af-reads with ZERO
// barriers (waves free-run; at 1 wave/SIMD each removed lockstep point was
// an unhidden ~150-250cy bubble). Z overlay reuses lA's first 16KB (A dead
// after MFMA phase; barrier-fenced). Per-step barriers: 11 -> 5.
__global__ __launch_bounds__(256, 1) void lstm_scan(
    ushort_t* __restrict__ seq,
    const ushort_t* __restrict__ Msum,
    const float* __restrict__ bias,
    const float* __restrict__ cin,
    int* __restrict__ bar)
{
    __shared__ __align__(16) ushort_t lA[8][4096];   // full A tile: 8 chunks x 8KB = 64KB

    const int tid = threadIdx.x, w = tid >> 6, lane = tid & 63;
    const int id = blockIdx.x;
    const int g  = id & 7;           // batch-row group (self-contained scan)
    const int s  = id >> 3;          // 0..31: h-col tile within group
    const int r0 = g << 5;           // 32 batch rows
    const int hb = s << 5;           // 32 h cols
    int* const barw = &bar[g << 5];  // group arrival counter (one line per group)

    // ---- resident B: wave w holds ntl = 2w, 2w+1; PINNED IN AGPRs (r7) ----
    bf16x8 Brg[2][32];
    #pragma unroll
    for (int n = 0; n < 2; ++n) {
        const int ntl = (w << 1) + n;
        const int gnt = (((s << 1) + (ntl >> 2)) << 2) + (ntl & 3);
        const ushort_t* bp = Msum + (((size_t)gnt << 5) << 9) + (lane << 3);
        #pragma unroll
        for (int ks = 0; ks < 32; ++ks) {
            Brg[n][ks] = *(const bf16x8*)(bp + ((size_t)ks << 9));
            asm volatile("" : "+a"(Brg[n][ks]));
        }
    }

    // ---- c-state + bias in registers: thread owns row=tid>>3, cols gu4..gu4+3 ----
    const int grow = tid >> 3, gu4 = (tid & 7) << 2;
    float c_reg[4], bi[4], bfv[4], bgv[4], bo[4];
    #pragma unroll
    for (int j = 0; j < 4; ++j) {
        int u = gu4 + j;
        c_reg[j] = cin[(size_t)(r0 + grow) * Hh + hb + u];
        bi[j]  = bias[       hb + u];
        bfv[j] = bias[1024 + hb + u];
        bgv[j] = bias[2048 + hb + u];
        bo[j]  = bias[3072 + hb + u];
    }

    float* lZ = (float*)lA;   // 32 x 128 f32 overlay (16KB, reuses A region)

    // A staging geometry: piece (c,i): row = i*16 + (tid>>4), k-chunk c, kp = tid&15
    const int kp  = tid & 15;
    const int q_a = kp & 3, kk_a = kp >> 2;
    const int mm_s  = tid >> 4;
    const int pos_s = (q_a << 4) | (mm_s ^ (((kk_a << 2) + q_a) & 15));
    const int lw0   = (((kk_a << 1) << 6) | pos_s) << 3;      // ushort idx; piece i adds 512
    const size_t ga0 = (size_t)(r0 + mm_s) * Hh + (kp << 3);  // global base; piece i adds 1<<14

    #pragma unroll 1
    for (int t = 1; t < Tt; ++t) {
        const ushort_t* Ap = seq + ((size_t)(t - 1) << 18) + ga0;

        f32x4 acc[2][2];
        #pragma unroll
        for (int m = 0; m < 2; ++m)
            #pragma unroll
            for (int n = 0; n < 2; ++n) acc[m][n] = (f32x4){0.f, 0.f, 0.f, 0.f};

        // ---- full-step prefetch: issue ALL 16 A-loads (oldest-first order
        // matches the write order below -> progressive counted vmcnt waits) ----
        bf16x8 rA[8][2];
        #pragma unroll
        for (int c = 0; c < 8; ++c)
            #pragma unroll
            for (int i = 0; i < 2; ++i)
                rA[c][i] = *(const bf16x8*)(Ap + (i << 14) + (c << 7));

        // ---- stage the WHOLE tile; one barrier; then barrier-free MFMA ----
        #pragma unroll
        for (int c = 0; c < 8; ++c)
            #pragma unroll
            for (int i = 0; i < 2; ++i)
                *(bf16x8*)&lA[c][lw0 + (i << 9)] = rA[c][i];
        lds_barrier();

        {
            const int qq = lane >> 4, mr = lane & 15;
            #pragma unroll
            for (int kc = 0; kc < 8; ++kc) {
                const ushort_t* lAc = lA[kc];
                #pragma unroll
                for (int kk = 0; kk < 4; ++kk) {
                    const int pos = (qq << 4) | (mr ^ (((kk << 2) + qq) & 15));
                    const int ks = (kc << 2) + kk;
                    bf16x8 af0 = *(const bf16x8*)&lAc[((((kk << 1) + 0) << 6) | pos) << 3];
                    bf16x8 af1 = *(const bf16x8*)&lAc[((((kk << 1) + 1) << 6) | pos) << 3];
                    acc[0][0] = __builtin_amdgcn_mfma_f32_16x16x32_bf16(af0, Brg[0][ks], acc[0][0], 0, 0, 0);
                    acc[0][1] = __builtin_amdgcn_mfma_f32_16x16x32_bf16(af0, Brg[1][ks], acc[0][1], 0, 0, 0);
                    acc[1][0] = __builtin_amdgcn_mfma_f32_16x16x32_bf16(af1, Brg[0][ks], acc[1][0], 0, 0, 0);
                    acc[1][1] = __builtin_amdgcn_mfma_f32_16x16x32_bf16(af1, Brg[1][ks], acc[1][1], 0, 0, 0);
                }
            }
        }
        lds_barrier();   // all af reads done -> safe to overwrite lA with Z

        // Z exchange into lZ (overlays lA), skew col+(5*row) -> <=2-way conflicts
        {
            const int q = lane >> 4, nl = lane & 15;
            #pragma unroll
            for (int m = 0; m < 2; ++m)
                #pragma unroll
                for (int n = 0; n < 2; ++n)
                    #pragma unroll
                    for (int r = 0; r < 4; ++r) {
                        int row = (m << 4) + (q << 2) + r;
                        int col = (((w << 1) + n) << 4) + nl;
                        lZ[(row << 7) + ((col + row * 5) & 127)] = acc[m][n][r];
                    }
        }
        lds_barrier();

        // gates + c/h update; h published via ONE relaxed agent-scope 8B atomic
        // exchange per thread (RMW lands at LLC -> visible to any consumer XCD)
        {
            const int rb5 = grow * 5;
            unsigned long long pk = 0;
            #pragma unroll
            for (int j = 0; j < 4; ++j) {
                int u = gu4 + j;
                int cb = ((u >> 4) << 6) + (u & 15);   // gate-0 Z col for this h col
                float zi = lZ[(grow << 7) + ((cb      + rb5) & 127)] + bi[j];
                float zf = lZ[(grow << 7) + ((cb + 16 + rb5) & 127)] + bfv[j];
                float zg = lZ[(grow << 7) + ((cb + 32 + rb5) & 127)] + bgv[j];
                float zo = lZ[(grow << 7) + ((cb + 48 + rb5) & 127)] + bo[j];
                float cn = sigf(zf) * c_reg[j] + sigf(zi) * tanhf_(zg);
                c_reg[j] = cn;
                pk |= (unsigned long long)f2bf(sigf(zo) * tanhf_(cn)) << (j << 4);
            }
            __hip_atomic_exchange(
                (unsigned long long*)&seq[((size_t)t << 18) +
                                          (size_t)(r0 + grow) * Hh + hb + gu4],
                pk, __ATOMIC_RELAXED, __HIP_MEMORY_SCOPE_AGENT);
        }

        if (t < Tt - 1) {
            __syncthreads();   // FULL drain: exchanges acked at the coherent point
            if (tid == 0) {
                // per-group barrier: agent-scope RMW arrival + RMW poll on one
                // LLC line (32 writers); no cross-group coupling
                __hip_atomic_fetch_add(barw, 1, __ATOMIC_RELAXED,
                                       __HIP_MEMORY_SCOPE_AGENT);
                int guard = 0;
                while (__hip_atomic_fetch_add(barw, 0, __ATOMIC_RELAXED,
                                              __HIP_MEMORY_SCOPE_AGENT) < (t << 5)
                       && ++guard < 30000)
                    __builtin_amdgcn_s_sleep(2);
            }
            lds_barrier();   // release: nothing outstanding to drain here
        }
    }
}

// ---------- batched emission, XCD-pinned, XOR-swizzled A staging ----------
__global__ __launch_bounds__(256) void emit(
    const ushort_t* __restrict__ seq,
    const ushort_t* __restrict__ Wsw,
    const float* __restrict__ bd,
    float* __restrict__ out)
{
    __shared__ __align__(16) ushort_t lA[2 * 8 * 64 * 8];
    __shared__ __align__(16) ushort_t lB[2 * 8 * 64 * 8];
    const int tid = threadIdx.x, w = tid >> 6, lane = tid & 63;
    const int id = blockIdx.x;
    const int rt = ((id >> 5) << 3) | (id & 7);
    const int ct = (id >> 3) & 3;
    const int r0 = rt << 7, f0 = ct << 7;
    const int wr = w >> 1, wc = w & 1;

    f32x4 acc[4][4];
    #pragma unroll
    for (int m = 0; m < 4; ++m)
        #pragma unroll
        for (int n = 0; n < 4; ++n) acc[m][n] = (f32x4){0.f, 0.f, 0.f, 0.f};

    for (int kc = 0; kc < Hh; kc += 64) {
        #pragma unroll
        for (int i = 0; i < 4; ++i) {
            int p = (i << 8) + tid;
            int row = p >> 3, kpp = p & 7;
            bf16x8 v = *(const bf16x8*)(seq + (size_t)(r0 + row) * Hh + kc + (kpp << 3));
            int kk = kpp >> 2, q = kpp & 3, msub = row >> 4, mm = row & 15;
            int pos = (q << 4) | (mm ^ (((kk << 2) + q) & 15));
            *(bf16x8*)&lA[((((kk << 3) + msub) << 6) + pos) << 3] = v;
        }
        #pragma unroll
        for (int i = 0; i < 4; ++i) {
            int d = (i << 8) + tid;
            int kk = d >> 9, csub = (d >> 6) & 7, ln = d & 63;
            int nt = (ct << 3) + csub;
            bf16x8 v = *(const bf16x8*)(Wsw + (((size_t)(nt * 32 + (kc >> 5) + kk)) << 9) + (ln << 3));
            *(bf16x8*)&lB[d << 3] = v;
        }
        __syncthreads();
        const int qq = lane >> 4, mm = lane & 15;
        #pragma unroll
        for (int kk = 0; kk < 2; ++kk) {
            const int pos = (qq << 4) | (mm ^ (((kk << 2) + qq) & 15));
            bf16x8 af[4], bfr[4];
            #pragma unroll
            for (int m = 0; m < 4; ++m)
                af[m] = *(const bf16x8*)&lA[((((kk << 3) + (wr << 2) + m) << 6) + pos) << 3];
            #pragma unroll
            for (int n = 0; n < 4; ++n)
                bfr[n] = *(const bf16x8*)&lB[((((kk << 3) + (wc << 2) + n) << 6) + lane) << 3];
            #pragma unroll
            for (int m = 0; m < 4; ++m)
                #pragma unroll
                for (int n = 0; n < 4; ++n)
                    acc[m][n] = __builtin_amdgcn_mfma_f32_16x16x32_bf16(
                        af[m], bfr[n], acc[m][n], 0, 0, 0);
        }
        __syncthreads();
    }

    int q = lane >> 4, nl = lane & 15;
    float bdv[4];
    #pragma unroll
    for (int n = 0; n < 4; ++n) bdv[n] = bd[f0 + (wc << 6) + (n << 4) + nl];
    #pragma unroll
    for (int m = 0; m < 4; ++m)
        #pragma unroll
        for (int r = 0; r < 4; ++r) {
            int grow2 = r0 + (wr << 6) + (m << 4) + (q << 2) + r;  // = t*256 + b
            int tt = grow2 >> 8, bb = grow2 & 255;
            float* op = out + ((size_t)((bb << 7) + tt) << 9);
            #pragma unroll
            for (int n = 0; n < 4; ++n)
                op[f0 + (wc << 6) + (n << 4) + nl] = acc[m][n][r] + bdv[n];
        }
}

// ---------- launch ----------
extern "C" void kernel_launch(void* const* d_in, const int* in_sizes, int n_in,
                              void* d_out, int out_size, void* d_ws, size_t ws_size,
                              hipStream_t stream)
{
    const float* x0 = (const float*)d_in[0];
    const float* h0 = (const float*)d_in[1];
    const float* c0 = (const float*)d_in[2];
    const float* W  = (const float*)d_in[3];
    const float* U  = (const float*)d_in[4];
    const float* b  = (const float*)d_in[5];
    const float* Wd = (const float*)d_in[6];
    const float* bd = (const float*)d_in[7];
    float* out = (float*)d_out;

    const size_t OFF_MCAT = 0;                  // 16,777,216
    const size_t OFF_MSUM = 16777216;           //  8,388,608
    const size_t OFF_WSW  = 25165824;           //  1,048,576
    const size_t OFF_A0   = 26214400;           //  1,048,576
    const size_t OFF_SEQ  = 27262976;           // 67,108,864
    const size_t OFF_BAR  = 94371840;           //      4,096
    const size_t WS_NEED  = 94375936;
    if (ws_size < WS_NEED) return;

    char* ws = (char*)d_ws;
    ushort_t* Mcat = (ushort_t*)(ws + OFF_MCAT);
    ushort_t* Msum = (ushort_t*)(ws + OFF_MSUM);
    ushort_t* Wsw  = (ushort_t*)(ws + OFF_WSW);
    ushort_t* A0   = (ushort_t*)(ws + OFF_A0);
    ushort_t* seq  = (ushort_t*)(ws + OFF_SEQ);
    int*      bar  = (int*)(ws + OFF_BAR);
    float* cws = out;   // c-state scratch: dead before emit overwrites out

    zero_bar<<<4, 256, 0, stream>>>(bar);
    mk_a0<<<2048, 256, 0, stream>>>(x0, h0, A0);
    swz<<<4096, 256, 0, stream>>>(W, U, Mcat, 2048, 4096, 1, 2048 * 4096);
    swz<<<2048, 256, 0, stream>>>(W, U, Msum, 1024, 4096, 0, 1024 * 4096);
    swz<<<512, 256, 0, stream>>>(Wd, nullptr, Wsw, 1024, 512, 2, 1024 * 512);

    lstm_step<<<256, 256, 0, stream>>>(A0, 2048, Mcat, c0, cws, seq, b);
    lstm_scan<<<256, 256, 0, stream>>>(seq, Msum, b, cws, bar);

    emit<<<1024, 256, 0, stream>>>(seq, Wsw, bd, out);
}